// Round 14
// baseline (467.791 us; speedup 1.0000x reference)
//
#include <hip/hip_runtime.h>

typedef unsigned short u16;
using bf16x8 = __attribute__((ext_vector_type(8))) short;
using f32x4  = __attribute__((ext_vector_type(4))) float;

#define SIB_SCALE_F 0.04419417382415922f   // 1/sqrt(512)

__device__ __forceinline__ u16 f2b(float f) {
  unsigned u = __builtin_bit_cast(unsigned, f);
  return (u16)((u + 0x7FFFu + ((u >> 16) & 1u)) >> 16);   // RNE
}

__device__ __forceinline__ float wred(float v) {
  #pragma unroll
  for (int m = 1; m < 64; m <<= 1) v += __shfl_xor(v, m);
  return v;
}

__device__ __forceinline__ void gload16(const void* g, void* l) {
  __builtin_amdgcn_global_load_lds(
      (const __attribute__((address_space(1))) unsigned int*)g,
      (__attribute__((address_space(3))) unsigned int*)l, 16, 0, 0);
}

// ---------------------------------------------------------------------------
// PERSISTENT 128x128 bf16 GEMM "gemmT": 2 blocks/CU (64KB LDS), 4 waves,
// continuous K-stream across m-tile seams.
// grid (2, 250): block (mg,by) computes rows [mg*MT*128,+MT*128) x cols
// [by*128,+128), MT=16 m-tiles visited in stagger order (by & 15).
// LDS: A[2][128][64] + B[2][128][64] u16, XOR slot swizzle (slot^=row&7),
// staged via gload16 pre-swizzled source.  Per kt (BK=64): 4 phases, phase p
// = m-frag p x n0-3 x kk0,1 (8 MFMA); stage A(g+1) at p0, B(g+2) at p2
// (B k-tiles cycle mod 8 -- same panel content every m-tile).
// Seam: acc snapshotted to pacc; 16 NT float4 stores issued at NEXT m-tile's
// kt0.p1 -- i.e. AFTER A(g+1)'s stage in issue order, so kt0.p3's vmcnt(20)
// certifies A(g+1) retired WITHOUT draining the stores (in-order vmem);
// stores drain one kt later under compute, hidden by the co-resident block.
// M % (128*MT*gridDim.x) == 0, K == 512 (NTK=8 hardcoded), N % 128 == 0.
// ---------------------------------------------------------------------------
__global__ __launch_bounds__(256, 2) void gemmT(
    const u16* __restrict__ A, const u16* __restrict__ B,
    const float* __restrict__ bias,
    float* __restrict__ C, int M, int N, int K, int MT)
{
  __shared__ u16 lds[32768];   // A: [0,16384) 2x8192 ; B: [16384,32768) 2x8192
  const int t = threadIdx.x, w = t >> 6, lane = t & 63;
  const int wm = w >> 1, wn = w & 1;          // 2m x 2n waves, wave-tile 64x64
  const int r16 = lane & 15, ks = lane >> 4;
  const int bn = blockIdx.y * 128;
  const int mg = blockIdx.x;
  const int stag = blockIdx.y & (MT - 1);

  // stage one 128x64 K-tile (16 KB): 4 gload16/thread, pre-swizzled source
  auto stageT = [&](const u16* __restrict__ G, int grow0, int ktile, int buf, int base) {
    const int k0 = ktile << 6;
    u16* dst = lds + base + (buf << 13);
    #pragma unroll
    for (int j = 0; j < 4; ++j) {
      const int r = j * 32 + w * 8 + (lane >> 3);
      const int s = (lane & 7) ^ (r & 7);
      gload16(G + (size_t)(grow0 + r) * K + k0 + s * 8,
              dst + j * 2048 + w * 512);
    }
  };

  float4 biasv[4];
  #pragma unroll
  for (int n = 0; n < 4; ++n)
    biasv[n] = *(const float4*)(bias + bn + wn * 64 + n * 16 + ks * 4);

  f32x4 acc[4][4], pacc[4][4];
  #pragma unroll
  for (int m = 0; m < 4; ++m)
    #pragma unroll
    for (int n = 0; n < 4; ++n) {
      f32x4 z = {0.f, 0.f, 0.f, 0.f};
      acc[m][n] = z; pacc[m][n] = z;
    }
  int bmPrev = 0;

  // prologue: A(0)->Abuf0, B(0)->Bbuf0, B(1)->Bbuf1; A(1) staged at kt0.p0
  {
    const int bm0 = (mg * MT + (stag & (MT - 1))) * 128;
    stageT(A, bm0, 0, 0, 0);
    stageT(B, bn, 0, 0, 16384);
    stageT(B, bn, 1, 1, 16384);
    asm volatile("s_waitcnt vmcnt(4)" ::: "memory");   // tile 0 landed
    __builtin_amdgcn_sched_barrier(0);
    __builtin_amdgcn_s_barrier();
  }

  for (int mt = 0; mt < MT; ++mt) {
    const int bm = (mg * MT + ((mt + stag) & (MT - 1))) * 128;
    const int bmNext = (mg * MT + ((mt + 1 + stag) & (MT - 1))) * 128;

    #pragma unroll
    for (int kt = 0; kt < 8; ++kt) {
      const u16* Ab = lds + ((kt & 1) << 13);
      const u16* Bb = lds + 16384 + ((kt & 1) << 13);
      bf16x8 bfr[4][2];

      #pragma unroll
      for (int p = 0; p < 4; ++p) {
        bf16x8 af[2];
        {
          const int row = wm * 64 + p * 16 + r16;
          af[0] = *(const bf16x8*)(Ab + row * 64 + ((ks ^ (row & 7)) << 3));
          af[1] = *(const bf16x8*)(Ab + row * 64 + (((4 + ks) ^ (row & 7)) << 3));
        }
        if (p == 0) {
          #pragma unroll
          for (int n = 0; n < 4; ++n) {
            const int row = wn * 64 + n * 16 + r16;
            bfr[n][0] = *(const bf16x8*)(Bb + row * 64 + ((ks ^ (row & 7)) << 3));
            bfr[n][1] = *(const bf16x8*)(Bb + row * 64 + (((4 + ks) ^ (row & 7)) << 3));
          }
          // stage A(g+1): next kt of this m-tile, or tile-0 of the next m-tile
          if (kt < 7)             stageT(A, bm,     kt + 1, (kt + 1) & 1, 0);
          else if (mt < MT - 1)   stageT(A, bmNext, 0,      0,            0);
        }
        if (p == 1 && kt == 0 && mt > 0) {
          // previous m-tile's stores: AFTER A(1)'s stage in issue order
          #pragma unroll
          for (int m = 0; m < 4; ++m) {
            const int grow = bmPrev + wm * 64 + m * 16 + r16;
            float* Crow = C + (size_t)grow * N;
            #pragma unroll
            for (int n = 0; n < 4; ++n) {
              const int gcol = bn + wn * 64 + n * 16 + ks * 4;
              f32x4 o;
              o[0] = pacc[m][n][0] + biasv[n].x;
              o[1] = pacc[m][n][1] + biasv[n].y;
              o[2] = pacc[m][n][2] + biasv[n].z;
              o[3] = pacc[m][n][3] + biasv[n].w;
              __builtin_nontemporal_store(o, (f32x4*)(Crow + gcol));
            }
          }
        }
        if (p == 2) {
          // stage B(g+2): k-tile (kt+2)&7, overwrites Bbuf[kt&1] (read done p0)
          if (kt < 6)             stageT(B, bn, kt + 2,       kt & 1, 16384);
          else if (mt < MT - 1)   stageT(B, bn, (kt + 2) & 7, kt & 1, 16384);
        }
        if (p == 3) {
          if (kt == 0) {
            if (mt > 0) { asm volatile("s_waitcnt vmcnt(20)" ::: "memory"); }
            else        { asm volatile("s_waitcnt vmcnt(4)"  ::: "memory"); }
          } else if (kt < 6) {
            asm volatile("s_waitcnt vmcnt(4)" ::: "memory");
          } else if (kt == 6) {
            if (mt < MT - 1) { asm volatile("s_waitcnt vmcnt(4)" ::: "memory"); }
            else             { asm volatile("s_waitcnt vmcnt(0)" ::: "memory"); }
          } else {  // kt == 7
            if (mt < MT - 1) { asm volatile("s_waitcnt vmcnt(4)" ::: "memory"); }
          }
          __builtin_amdgcn_sched_barrier(0);
        }
        __builtin_amdgcn_s_barrier();
        asm volatile("s_waitcnt lgkmcnt(0)" ::: "memory");
        __builtin_amdgcn_sched_barrier(0);
        __builtin_amdgcn_s_setprio(1);
        #pragma unroll
        for (int n = 0; n < 4; ++n) {
          acc[p][n] = __builtin_amdgcn_mfma_f32_16x16x32_bf16(bfr[n][0], af[0], acc[p][n], 0, 0, 0);
          acc[p][n] = __builtin_amdgcn_mfma_f32_16x16x32_bf16(bfr[n][1], af[1], acc[p][n], 0, 0, 0);
        }
        __builtin_amdgcn_s_setprio(0);
        __builtin_amdgcn_s_barrier();
      }
    }

    // m-tile end: snapshot acc for spread stores, reset acc
    bmPrev = bm;
    #pragma unroll
    for (int m = 0; m < 4; ++m)
      #pragma unroll
      for (int n = 0; n < 4; ++n) {
        pacc[m][n] = acc[m][n];
        f32x4 z = {0.f, 0.f, 0.f, 0.f};
        acc[m][n] = z;
      }
  }

  // final m-tile's stores
  #pragma unroll
  for (int m = 0; m < 4; ++m) {
    const int grow = bmPrev + wm * 64 + m * 16 + r16;
    float* Crow = C + (size_t)grow * N;
    #pragma unroll
    for (int n = 0; n < 4; ++n) {
      const int gcol = bn + wn * 64 + n * 16 + ks * 4;
      f32x4 o;
      o[0] = pacc[m][n][0] + biasv[n].x;
      o[1] = pacc[m][n][1] + biasv[n].y;
      o[2] = pacc[m][n][2] + biasv[n].z;
      o[3] = pacc[m][n][3] + biasv[n].w;
      __builtin_nontemporal_store(o, (f32x4*)(Crow + gcol));
    }
  }
}

// ---------------------------------------------------------------------------
// Small GEMM, 64x128 tile, BK=32, 256 thr (4 waves, 1m x 4n, wave-tile
// 64x32), swapped-operand float4 epilogue.  C = A@B^T + bscale*bias[lvl].
// GATHER: A rows = bf16(Afp[tok[row]]), K must be 512.
// ---------------------------------------------------------------------------
template <bool GATHER>
__global__ __launch_bounds__(256) void gemm64(
    const float* __restrict__ Afp, const int* __restrict__ tok,
    const u16* __restrict__ A, const u16* __restrict__ B,
    const float* __restrict__ bias, int blvl, float bscale,
    float* __restrict__ C, u16* __restrict__ Cb,
    int M, int N, int K)
{
  __shared__ u16 ldsA[64 * 32];    // 4 KB
  __shared__ u16 ldsB[128 * 32];   // 8 KB
  const int t = threadIdx.x, w = t >> 6, lane = t & 63;
  const int r16 = lane & 15, ks = lane >> 4;

  const int nb = gridDim.x * gridDim.y;
  const int lid = blockIdx.y * gridDim.x + blockIdx.x;
  const int chunk = nb >> 3;
  const int nlid = (lid & 7) * chunk + (lid >> 3);
  const int bm = (nlid % gridDim.x) * 64;
  const int bn = (nlid / gridDim.x) * 128;

  const int srow = t >> 2, sslot = t & 3;

  f32x4 acc[4][2];
  #pragma unroll
  for (int m = 0; m < 4; ++m)
    #pragma unroll
    for (int n = 0; n < 2; ++n) {
      f32x4 z = {0.f, 0.f, 0.f, 0.f};
      acc[m][n] = z;
    }

  for (int k0 = 0; k0 < K; k0 += 32) {
    if (k0) __syncthreads();
    {
      const int row = srow;                       // 0..63
      const int sl = sslot ^ ((row >> 1) & 3);
      if constexpr (GATHER) {
        const float* src = Afp + (size_t)tok[bm + row] * 512 + k0 + sl * 8;
        const float4 a0 = *(const float4*)src;
        const float4 a1 = *(const float4*)(src + 4);
        bf16x8 v;
        v[0] = (short)f2b(a0.x); v[1] = (short)f2b(a0.y);
        v[2] = (short)f2b(a0.z); v[3] = (short)f2b(a0.w);
        v[4] = (short)f2b(a1.x); v[5] = (short)f2b(a1.y);
        v[6] = (short)f2b(a1.z); v[7] = (short)f2b(a1.w);
        *(bf16x8*)(ldsA + t * 8) = v;
      } else {
        gload16(A + (size_t)(bm + row) * K + k0 + sl * 8, ldsA + w * 512);
      }
    }
    #pragma unroll
    for (int i = 0; i < 2; ++i) {
      const int row = i * 64 + srow;
      const int sl = sslot ^ ((row >> 1) & 3);
      gload16(B + (size_t)(bn + row) * K + k0 + sl * 8,
              ldsB + i * 2048 + w * 512);
    }
    __syncthreads();

    bf16x8 af[4], bfr[2];
    #pragma unroll
    for (int m = 0; m < 4; ++m) {
      const int row = m * 16 + r16;
      af[m] = *(const bf16x8*)(ldsA + row * 32 + ((ks ^ ((row >> 1) & 3)) << 3));
    }
    #pragma unroll
    for (int n = 0; n < 2; ++n) {
      const int row = w * 32 + n * 16 + r16;
      bfr[n] = *(const bf16x8*)(ldsB + row * 32 + ((ks ^ ((row >> 1) & 3)) << 3));
    }
    #pragma unroll
    for (int m = 0; m < 4; ++m)
      #pragma unroll
      for (int n = 0; n < 2; ++n)
        acc[m][n] = __builtin_amdgcn_mfma_f32_16x16x32_bf16(bfr[n], af[m], acc[m][n], 0, 0, 0);
  }

  const float* be = bias + (size_t)(bm >> 12) * blvl;
  #pragma unroll
  for (int m = 0; m < 4; ++m) {
    const int grow = bm + m * 16 + r16;
    #pragma unroll
    for (int n = 0; n < 2; ++n) {
      const int gcol = bn + w * 32 + n * 16 + ks * 4;
      const float4 bv = *(const float4*)(be + gcol);
      float4 o;
      o.x = acc[m][n][0] + bv.x * bscale;
      o.y = acc[m][n][1] + bv.y * bscale;
      o.z = acc[m][n][2] + bv.z * bscale;
      o.w = acc[m][n][3] + bv.w * bscale;
      const size_t idx = (size_t)grow * N + gcol;
      *(float4*)(C + idx) = o;
      if (Cb) {
        ushort4 ob = { f2b(o.x), f2b(o.y), f2b(o.z), f2b(o.w) };
        *(ushort4*)(Cb + idx) = ob;
      }
    }
  }
}

// ---------------------------------------------------------------------------
// bf16 MFMA GEMM, 128x128 tile, BK=32, swapped-operand epilogue (S3+POOL).
// ---------------------------------------------------------------------------
__global__ __launch_bounds__(256) void gemm_pool(
    const u16* __restrict__ A, const u16* __restrict__ B,
    const float* __restrict__ bias, float bscale,
    const float* __restrict__ h0f, const float* __restrict__ S1f,
    const float* __restrict__ S2f, const float* __restrict__ psum,
    u16* __restrict__ P,
    int M, int N, int K)
{
  __shared__ u16 ldsA[128 * 32];
  __shared__ u16 ldsB[128 * 32];
  const int t = threadIdx.x;
  const int w = t >> 6;
  const int lane = t & 63;
  const int wr = w >> 1, wc = w & 1;

  const int nb = gridDim.x * gridDim.y;
  const int lid = blockIdx.y * gridDim.x + blockIdx.x;
  const int chunk = nb >> 3;
  const int nlid = (lid & 7) * chunk + (lid >> 3);
  const int bx = nlid % gridDim.x, by = nlid / gridDim.x;

  const int bm = bx * 128, bn = by * 128;
  const int r16 = lane & 15, ks = lane >> 4;
  const int srow = t >> 2, sslot = t & 3;

  f32x4 acc[4][4];
  #pragma unroll
  for (int m = 0; m < 4; ++m)
    #pragma unroll
    for (int n = 0; n < 4; ++n) {
      f32x4 z = {0.f, 0.f, 0.f, 0.f};
      acc[m][n] = z;
    }

  for (int k0 = 0; k0 < K; k0 += 32) {
    if (k0) __syncthreads();
    #pragma unroll
    for (int i = 0; i < 2; ++i) {
      const int row = srow + i * 64;
      const int sl = sslot ^ ((row >> 1) & 3);
      gload16(A + (size_t)(bm + row) * K + k0 + sl * 8,
              ldsA + (i * 2048 + w * 512));
      gload16(B + (size_t)(bn + row) * K + k0 + sl * 8,
              ldsB + (i * 2048 + w * 512));
    }
    __syncthreads();

    bf16x8 af[4], bfr[4];
    #pragma unroll
    for (int m = 0; m < 4; ++m) {
      const int row = wr * 64 + m * 16 + r16;
      af[m] = *(const bf16x8*)(ldsA + row * 32 + ((ks ^ ((row >> 1) & 3)) << 3));
    }
    #pragma unroll
    for (int n = 0; n < 4; ++n) {
      const int row = wc * 64 + n * 16 + r16;
      bfr[n] = *(const bf16x8*)(ldsB + row * 32 + ((ks ^ ((row >> 1) & 3)) << 3));
    }
    #pragma unroll
    for (int m = 0; m < 4; ++m)
      #pragma unroll
      for (int n = 0; n < 4; ++n)
        acc[m][n] = __builtin_amdgcn_mfma_f32_16x16x32_bf16(bfr[n], af[m], acc[m][n], 0, 0, 0);
  }

  const float a0 = (psum[0] * (1.f / 4096.f) >= 0.5f) ? 1.f : 0.f;
  const float a1 = a0 * ((psum[1] * (1.f / 4096.f) >= 0.5f) ? 1.f : 0.f);
  const float a2 = a1 * ((psum[2] * (1.f / 4096.f) >= 0.5f) ? 1.f : 0.f);
  const float cnt = 1.f + a0 * 2.f + a1 * 4.f + a2 * 8.f;
  const float inv = 1.f / fmaxf(cnt, 1e-8f);

  #pragma unroll
  for (int m = 0; m < 4; ++m) {
    const int grow = bm + wr * 64 + m * 16 + r16;
    #pragma unroll
    for (int n = 0; n < 4; ++n) {
      const int gcol = bn + wc * 64 + n * 16 + ks * 4;
      const float4 bv = *(const float4*)(bias + gcol);
      float4 o;
      o.x = acc[m][n][0] + bv.x * bscale;
      o.y = acc[m][n][1] + bv.y * bscale;
      o.z = acc[m][n][2] + bv.z * bscale;
      o.w = acc[m][n][3] + bv.w * bscale;
      const size_t idx = (size_t)grow * N + gcol;
      const float4 h = *(const float4*)(h0f + idx);
      const float4 s1 = *(const float4*)(S1f + idx);
      const float4 s2 = *(const float4*)(S2f + idx);
      ushort4 ob;
      ob.x = f2b((h.x + a0 * s1.x + a1 * s2.x + a2 * o.x) * inv);
      ob.y = f2b((h.y + a0 * s1.y + a1 * s2.y + a2 * o.y) * inv);
      ob.z = f2b((h.z + a0 * s1.z + a1 * s2.z + a2 * o.z) * inv);
      ob.w = f2b((h.w + a0 * s1.w + a1 * s2.w + a2 * o.w) * inv);
      *(ushort4*)(P + idx) = ob;
    }
  }
}

// ---------------------------------------------------------------------------
// fused weight prep + out_w conversion, role-dispatched (grid 16676)
// ---------------------------------------------------------------------------
__global__ __launch_bounds__(256) void prep_misc(
    const float* __restrict__ cf_w, const float* __restrict__ cf_b,
    const float* __restrict__ sib, const float* __restrict__ proj_w,
    const float* __restrict__ f1w, const float* __restrict__ f1b,
    const float* __restrict__ f2w, const float* __restrict__ pde,
    const float* __restrict__ out_w,
    u16* __restrict__ wsum_b, u16* __restrict__ projw_b,
    u16* __restrict__ f1w512b, u16* __restrict__ f2wb,
    float* __restrict__ cvec, float* __restrict__ psum,
    float* __restrict__ y1bias, u16* __restrict__ outw_b)
{
  const int b = blockIdx.x, t = threadIdx.x;
  if (b >= 676) {
    const int idx = (b - 676) * 256 + t;
    const float4 v = ((const float4*)out_w)[idx];
    ushort4 o = { f2b(v.x), f2b(v.y), f2b(v.z), f2b(v.w) };
    ((ushort4*)outw_b)[idx] = o;
  } else if (b < 256) {
    const int idx = b * 256 + t;
    const float4 a = ((const float4*)cf_w)[idx];
    const float4 c = ((const float4*)(cf_w + 262144))[idx];
    ushort4 o = { f2b(a.x + c.x), f2b(a.y + c.y), f2b(a.z + c.z), f2b(a.w + c.w) };
    ((ushort4*)wsum_b)[idx] = o;
  } else if (b < 512) {
    const int idx = (b - 256) * 256 + t;
    const float4 v = ((const float4*)proj_w)[idx];
    ushort4 o = { f2b(v.x), f2b(v.y), f2b(v.z), f2b(v.w) };
    ((ushort4*)projw_b)[idx] = o;
  } else if (b < 640) {
    const int fi = (b - 512) * 256 + t;
    const int row = fi >> 7, c4 = fi & 127;
    const float4 v = *(const float4*)(f1w + (size_t)row * 640 + c4 * 4);
    ushort4 o = { f2b(v.x), f2b(v.y), f2b(v.z), f2b(v.w) };
    ((ushort4*)f1w512b)[row * 128 + c4] = o;
  } else if (b < 672) {
    const int idx = (b - 640) * 256 + t;
    const float4 v = ((const float4*)f2w)[idx];
    ushort4 o = { f2b(v.x), f2b(v.y), f2b(v.z), f2b(v.w) };
    ((ushort4*)f2wb)[idx] = o;
  } else if (b < 675) {
    const int l = b - 672, j = t;
    const float* wrow = f1w + (size_t)j * 640 + 512;
    const float* p = pde + l * 128;
    float s = f1b[j];
    #pragma unroll 4
    for (int k = 0; k < 128; ++k) s += wrow[k] * p[k];
    y1bias[l * 256 + j] = s;
  } else {
    cvec[t]       = cf_b[t]       + cf_b[512 + t] + SIB_SCALE_F * (sib[t]       + sib[512 + t]);
    cvec[256 + t] = cf_b[256 + t] + cf_b[768 + t] + SIB_SCALE_F * (sib[256 + t] + sib[768 + t]);
    if (t < 3) psum[t] = 0.f;
  }
}

// ---------------------------------------------------------------------------
// batched policy input over 3 levels: X[g] = bf16(LN(S_l/2^l + 0.01*dep_l))
// ---------------------------------------------------------------------------
__global__ __launch_bounds__(256) void mean_ln_concat_b(
    const float* __restrict__ S0, const float* __restrict__ S1,
    const float* __restrict__ S2,
    const float* __restrict__ dep,
    const float* __restrict__ g, const float* __restrict__ b,
    u16* __restrict__ X)
{
  const int wid = threadIdx.x >> 6, lane = threadIdx.x & 63;
  const int gr = blockIdx.x * 4 + wid;          // 0..12287
  const int l = gr >> 12, n = gr & 4095;
  const float* Sr = (l == 0 ? S0 : l == 1 ? S1 : S2) + (size_t)n * 512;
  const float invM = (l == 0 ? 1.f : l == 1 ? 0.5f : 0.25f);
  const float* depl = dep + 512 * l;
  const int c0 = lane * 8;
  float x[8];
  float s = 0.f, sq = 0.f;
  #pragma unroll
  for (int i = 0; i < 8; ++i) {
    const float v = Sr[c0 + i] * invM + 0.01f * depl[c0 + i];
    x[i] = v; s += v; sq += v * v;
  }
  s = wred(s); sq = wred(sq);
  const float mean = s * (1.f / 512.f);
  const float var = sq * (1.f / 512.f) - mean * mean;
  const float rs = rsqrtf(var + 1e-5f);
  ushort4 o0, o1;
  o0.x = f2b((x[0] - mean) * rs * g[c0 + 0] + b[c0 + 0]);
  o0.y = f2b((x[1] - mean) * rs * g[c0 + 1] + b[c0 + 1]);
  o0.z = f2b((x[2] - mean) * rs * g[c0 + 2] + b[c0 + 2]);
  o0.w = f2b((x[3] - mean) * rs * g[c0 + 3] + b[c0 + 3]);
  o1.x = f2b((x[4] - mean) * rs * g[c0 + 4] + b[c0 + 4]);
  o1.y = f2b((x[5] - mean) * rs * g[c0 + 5] + b[c0 + 5]);
  o1.z = f2b((x[6] - mean) * rs * g[c0 + 6] + b[c0 + 6]);
  o1.w = f2b((x[7] - mean) * rs * g[c0 + 7] + b[c0 + 7]);
  ushort4* Xr = (ushort4*)(X + (size_t)gr * 512);
  Xr[lane * 2]     = o0;
  Xr[lane * 2 + 1] = o1;
}

// LN + relu over 256 cols, fp32 in -> bf16 out
__global__ __launch_bounds__(256) void ln_relu_b256(
    const float* __restrict__ X, const float* __restrict__ g,
    const float* __restrict__ b, u16* __restrict__ O)
{
  const int wid = threadIdx.x >> 6, lane = threadIdx.x & 63;
  const int n = blockIdx.x * 4 + wid;
  const float* Xr = X + (size_t)n * 256;
  float x[4];
  float s = 0.f, sq = 0.f;
  #pragma unroll
  for (int i = 0; i < 4; ++i) {
    x[i] = Xr[lane * 4 + i]; s += x[i]; sq += x[i] * x[i];
  }
  s = wred(s); sq = wred(sq);
  const float mean = s * (1.f / 256.f);
  const float var = sq * (1.f / 256.f) - mean * mean;
  const float rs = rsqrtf(var + 1e-5f);
  ushort4 o;
  o.x = f2b(fmaxf((x[0] - mean) * rs * g[lane * 4 + 0] + b[lane * 4 + 0], 0.f));
  o.y = f2b(fmaxf((x[1] - mean) * rs * g[lane * 4 + 1] + b[lane * 4 + 1], 0.f));
  o.z = f2b(fmaxf((x[2] - mean) * rs * g[lane * 4 + 2] + b[lane * 4 + 2], 0.f));
  o.w = f2b(fmaxf((x[3] - mean) * rs * g[lane * 4 + 3] + b[lane * 4 + 3], 0.f));
  ((ushort4*)(O + (size_t)n * 256))[lane] = o;
}

// fused: LN(128) + relu + dot(pow_w) + sigmoid + clip + per-level atomicAdd
__global__ __launch_bounds__(256) void ln_policy128(
    const float* __restrict__ Y2, const float* __restrict__ g,
    const float* __restrict__ b, const float* __restrict__ pw,
    const float* __restrict__ pb, float* __restrict__ psum)
{
  __shared__ float part[4];
  const int wid = threadIdx.x >> 6, lane = threadIdx.x & 63;
  const int gr = blockIdx.x * 4 + wid;
  const float* Xr = Y2 + (size_t)gr * 128;
  float x[2];
  float s = 0.f, sq = 0.f;
  #pragma unroll
  for (int i = 0; i < 2; ++i) {
    x[i] = Xr[lane * 2 + i]; s += x[i]; sq += x[i] * x[i];
  }
  s = wred(s); sq = wred(sq);
  const float mean = s * (1.f / 128.f);
  const float var = sq * (1.f / 128.f) - mean * mean;
  const float rs = rsqrtf(var + 1e-5f);
  float z = 0.f;
  #pragma unroll
  for (int i = 0; i < 2; ++i) {
    const int c = lane * 2 + i;
    const float v = fmaxf((x[i] - mean) * rs * g[c] + b[c], 0.f);
    z += v * pw[c];
  }
  z = wred(z);
  if (lane == 0) {
    const float p = 1.f / (1.f + expf(-(z + pb[0])));
    part[wid] = fminf(fmaxf(p, 1e-7f), 1.f - 1e-7f);
  }
  __syncthreads();
  if (threadIdx.x == 0)
    atomicAdd(psum + (gr >> 12), part[0] + part[1] + part[2] + part[3]);
}

// ---------------------------------------------------------------------------
extern "C" void kernel_launch(void* const* d_in, const int* in_sizes, int n_in,
                              void* d_out, int out_size, void* d_ws, size_t ws_size,
                              hipStream_t stream) {
  const int*   tok    = (const int*)  d_in[0];
  const float* emb    = (const float*)d_in[1];
  const float* proj_w = (const float*)d_in[2];
  const float* proj_b = (const float*)d_in[3];
  const float* cf_w   = (const float*)d_in[4];
  const float* cf_b   = (const float*)d_in[5];
  const float* in_g   = (const float*)d_in[6];
  const float* in_b   = (const float*)d_in[7];
  const float* pde    = (const float*)d_in[8];
  const float* f1w    = (const float*)d_in[9];
  const float* f1b    = (const float*)d_in[10];
  const float* n1g    = (const float*)d_in[11];
  const float* n1b    = (const float*)d_in[12];
  const float* f2w    = (const float*)d_in[13];
  const float* f2bias = (const float*)d_in[14];
  const float* n2g    = (const float*)d_in[15];
  const float* n2b    = (const float*)d_in[16];
  const float* pow_w  = (const float*)d_in[17];
  const float* pow_b  = (const float*)d_in[18];
  const float* sib    = (const float*)d_in[19];
  const float* dep    = (const float*)d_in[20];
  const float* out_w  = (const float*)d_in[21];
  const float* out_b  = (const float*)d_in[22];
  float* out = (float*)d_out;

  char* ws = (char*)d_ws;
  size_t off = 0;
  auto alloc = [&](size_t bytes) -> void* {
    void* p = ws + off;
    off += (bytes + 255) & ~(size_t)255;
    return p;
  };
  u16*   outw_b  = (u16*)  alloc((size_t)32000 * 512 * 2);
  u16*   projw_b = (u16*)  alloc((size_t)512 * 512 * 2);
  u16*   wsum_b  = (u16*)  alloc((size_t)512 * 512 * 2);
  u16*   f1w512b = (u16*)  alloc((size_t)256 * 512 * 2);
  u16*   f2wb    = (u16*)  alloc((size_t)128 * 256 * 2);
  float* h0f     = (float*)alloc((size_t)4096 * 512 * 4);
  u16*   h0b     = (u16*)  alloc((size_t)4096 * 512 * 2);
  float* S1f     = (float*)alloc((size_t)4096 * 512 * 4);
  u16*   S1b     = (u16*)  alloc((size_t)4096 * 512 * 2);
  float* S2f     = (float*)alloc((size_t)4096 * 512 * 4);
  u16*   S2b     = (u16*)  alloc((size_t)4096 * 512 * 2);
  u16*   X       = (u16*)  alloc((size_t)12288 * 512 * 2);
  float* Y1      = (float*)alloc((size_t)12288 * 256 * 4);
  u16*   Y1b     = (u16*)  alloc((size_t)12288 * 256 * 2);
  float* Y2      = (float*)alloc((size_t)12288 * 128 * 4);
  float* y1bias  = (float*)alloc(3 * 256 * 4);
  float* cvec    = (float*)alloc(512 * 4);
  float* psum    = (float*)alloc(256);
  u16*   poolb   = (u16*)  alloc((size_t)4096 * 512 * 2);

  prep_misc<<<16676, 256, 0, stream>>>(cf_w, cf_b, sib, proj_w, f1w, f1b, f2w,
                                       pde, out_w,
                                       wsum_b, projw_b, f1w512b, f2wb,
                                       cvec, psum, y1bias, outw_b);

  // h0 = emb[tok] @ proj_w^T + proj_b
  gemm64<true><<<dim3(64, 4), 256, 0, stream>>>(
      emb, tok, nullptr, projw_b, proj_b, 0, 1.f, h0f, h0b, 4096, 512, 512);
  // S1, S2
  gemm64<false><<<dim3(64, 4), 256, 0, stream>>>(
      nullptr, nullptr, h0b, wsum_b, cvec, 0, 1.f, S1f, S1b, 4096, 512, 512);
  gemm64<false><<<dim3(64, 4), 256, 0, stream>>>(
      nullptr, nullptr, S1b, wsum_b, cvec, 0, 2.f, S2f, S2b, 4096, 512, 512);

  // policy, 3 levels batched
  mean_ln_concat_b<<<3072, 256, 0, stream>>>(h0f, S1f, S2f, dep, in_g, in_b, X);
  gemm64<false><<<dim3(192, 2), 256, 0, stream>>>(
      nullptr, nullptr, X, f1w512b, y1bias, 256, 1.f, Y1, nullptr, 12288, 256, 512);
  ln_relu_b256<<<3072, 256, 0, stream>>>(Y1, n1g, n1b, Y1b);
  gemm64<false><<<dim3(192, 1), 256, 0, stream>>>(
      nullptr, nullptr, Y1b, f2wb, f2bias, 0, 1.f, Y2, nullptr, 12288, 128, 256);
  ln_policy128<<<3072, 256, 0, stream>>>(Y2, n2g, n2b, pow_w, pow_b, psum);

  // S3 GEMM fused with pooling (128^2, proven)
  gemm_pool<<<dim3(32, 4), 256, 0, stream>>>(
      S2b, wsum_b, cvec, 4.f, h0f, S1f, S2f, psum, poolb, 4096, 512, 512);

  // out = pooled @ out_w^T + out_b (4096 x 32000 x 512)
  // persistent 128x128, 2 blocks/CU, continuous K-stream, spread NT stores
  gemmT<<<dim3(2, 250), 256, 0, stream>>>(poolb, outw_b, out_b,
                                          out, 4096, 32000, 512, 16);
}

// Round 17
// 397.649 us; speedup vs baseline: 1.1764x; 1.1764x over previous
//
#include <hip/hip_runtime.h>

typedef unsigned short u16;
using bf16x8 = __attribute__((ext_vector_type(8))) short;
using f32x4  = __attribute__((ext_vector_type(4))) float;

#define SIB_SCALE_F 0.04419417382415922f   // 1/sqrt(512)

__device__ __forceinline__ u16 f2b(float f) {
  unsigned u = __builtin_bit_cast(unsigned, f);
  return (u16)((u + 0x7FFFu + ((u >> 16) & 1u)) >> 16);   // RNE
}

__device__ __forceinline__ float wred(float v) {
  #pragma unroll
  for (int m = 1; m < 64; m <<= 1) v += __shfl_xor(v, m);
  return v;
}

__device__ __forceinline__ void gload16(const void* g, void* l) {
  __builtin_amdgcn_global_load_lds(
      (const __attribute__((address_space(1))) unsigned int*)g,
      (__attribute__((address_space(3))) unsigned int*)l, 16, 0, 0);
}

// ---------------------------------------------------------------------------
// B-RESIDENT final GEMM "gemmV": C[M,N] = A@B^T + bias, fp32 out.
// Block = one 128-col B panel staged into LDS ONCE (128KB) and reused for
// all 32 m-tiles; A streams via THREE-buffered 8KB tiles (BK=32).
// R17 FIX: lds size 77824 u16 (B 65536 + A 3x4096 = 12288).  R15/R16 sized
// it 73728 (only 2 A-bufs) -> buf2 was OUT OF BOUNDS -> every third K-tile
// read garbage -> deterministic absmax 0.064.
// Sync (order-robust): uniform entry vmcnt(2) -- draining to the 2 newest
// ops always retires A(g) under ANY compiler interleave.  Seam stores
// (regular float4) at kt0 BEFORE stageA, pinned by sched_barrier(0); they
// drain at kt1's vmcnt(2).  m-tile order staggered per block.
// grid = 250.  M==4096, K==512 hardcoded via loop bounds.  LDS 152KB.
// ---------------------------------------------------------------------------
__global__ __launch_bounds__(256, 1) void gemmV(
    const u16* __restrict__ A, const u16* __restrict__ B,
    const float* __restrict__ bias,
    float* __restrict__ C, int M, int N, int K)
{
  __shared__ u16 lds[77824];   // B: [0,65536) ; A: [65536,77824) = 3 x 4096 u16
  const int t = threadIdx.x, w = t >> 6, lane = t & 63;
  const int wm = w >> 1, wn = w & 1;          // 2m x 2n, wave-tile 64x64
  const int r16 = lane & 15, ks = lane >> 4;
  const int bn = blockIdx.x * 128;
  const int stag = blockIdx.x & 31;

  // ---- stage the full B panel: wave w stages col (i*4+w), pre-swizzled ----
  #pragma unroll 4
  for (int i = 0; i < 32; ++i) {
    const int c = i * 4 + w;
    const int ksrc = (lane & ~7) | ((lane & 7) ^ (c & 7));
    gload16(B + (size_t)(bn + c) * 512 + ksrc * 8, lds + c * 512);
  }

  // A tile stage: 128 rows x 32 K (8 KB) into buf (2 gload16/thread)
  auto stageA = [&](int bmT, int kt, int buf) {
    u16* dst = lds + 65536 + buf * 4096;
    #pragma unroll
    for (int j = 0; j < 2; ++j) {
      const int r = j * 64 + w * 16 + (lane >> 2);
      const int s = (lane & 3) ^ (r & 3);
      gload16(A + (size_t)(bmT + r) * 512 + kt * 32 + s * 8,
              dst + j * 2048 + w * 512);
    }
  };

  float4 biasv[4];
  #pragma unroll
  for (int n = 0; n < 4; ++n)
    biasv[n] = *(const float4*)(bias + bn + wn * 64 + n * 16 + ks * 4);

  f32x4 acc[4][4], pacc[4][4];
  #pragma unroll
  for (int m = 0; m < 4; ++m)
    #pragma unroll
    for (int n = 0; n < 4; ++n) {
      f32x4 z = {0.f, 0.f, 0.f, 0.f};
      acc[m][n] = z; pacc[m][n] = z;
    }
  int bmPrev = 0;

  // prologue: A(0), A(1) of first m-tile; vmcnt(2) drains B + A(0)
  {
    const int bm0 = (stag & 31) * 128;
    stageA(bm0, 0, 0);
    stageA(bm0, 1, 1);
    asm volatile("s_waitcnt vmcnt(2)" ::: "memory");
    __builtin_amdgcn_sched_barrier(0);
  }

  int bufR = 0;   // g % 3
  for (int mt = 0; mt < 32; ++mt) {
    const int bm  = ((mt + stag) & 31) * 128;
    const int bmN = ((mt + 1 + stag) & 31) * 128;

    #pragma unroll
    for (int kt = 0; kt < 16; ++kt) {
      const int g = mt * 16 + kt;
      if (g > 0) {
        if (g == 511) asm volatile("s_waitcnt vmcnt(0)" ::: "memory");
        else          asm volatile("s_waitcnt vmcnt(2)" ::: "memory");
        __builtin_amdgcn_sched_barrier(0);
      }
      __builtin_amdgcn_s_barrier();

      const u16* Ab = lds + 65536 + bufR * 4096;
      bf16x8 af[4], bfr[4];
      #pragma unroll
      for (int m = 0; m < 4; ++m) {
        const int row = wm * 64 + m * 16 + r16;
        af[m] = *(const bf16x8*)(Ab + row * 32 + ((ks ^ (row & 3)) << 3));
      }
      #pragma unroll
      for (int n = 0; n < 4; ++n) {
        const int col = wn * 64 + n * 16 + r16;
        bfr[n] = *(const bf16x8*)(lds + col * 512 + (kt >> 1) * 64 +
                                  ((((kt & 1) * 4 + ks) ^ (col & 7)) << 3));
      }

      // ---- seam stores (previous m-tile), BEFORE the A stage, pinned ----
      if (kt == 0 && mt > 0) {
        __builtin_amdgcn_sched_barrier(0);
        #pragma unroll
        for (int m = 0; m < 4; ++m) {
          const int grow = bmPrev + wm * 64 + m * 16 + r16;
          float* Crow = C + (size_t)grow * N;
          #pragma unroll
          for (int n = 0; n < 4; ++n) {
            const int gcol = bn + wn * 64 + n * 16 + ks * 4;
            float4 o;
            o.x = pacc[m][n][0] + biasv[n].x;
            o.y = pacc[m][n][1] + biasv[n].y;
            o.z = pacc[m][n][2] + biasv[n].z;
            o.w = pacc[m][n][3] + biasv[n].w;
            *(float4*)(Crow + gcol) = o;
          }
        }
        __builtin_amdgcn_sched_barrier(0);
      }

      // ---- stage A(g+2) ----
      if (g + 2 < 512) {
        const int kt2 = kt + 2;
        const int bm2 = (kt2 < 16) ? bm : bmN;
        stageA(bm2, kt2 & 15, (bufR + 2) % 3);
      }

      asm volatile("s_waitcnt lgkmcnt(0)" ::: "memory");
      __builtin_amdgcn_sched_barrier(0);
      __builtin_amdgcn_s_setprio(1);
      #pragma unroll
      for (int m = 0; m < 4; ++m)
        #pragma unroll
        for (int n = 0; n < 4; ++n)
          acc[m][n] = __builtin_amdgcn_mfma_f32_16x16x32_bf16(bfr[n], af[m], acc[m][n], 0, 0, 0);
      __builtin_amdgcn_s_setprio(0);

      if (kt == 15) {
        bmPrev = bm;
        #pragma unroll
        for (int m = 0; m < 4; ++m)
          #pragma unroll
          for (int n = 0; n < 4; ++n) {
            pacc[m][n] = acc[m][n];
            f32x4 z = {0.f, 0.f, 0.f, 0.f};
            acc[m][n] = z;
          }
      }
      bufR = (bufR + 1) % 3;
    }
  }

  // final m-tile's stores
  #pragma unroll
  for (int m = 0; m < 4; ++m) {
    const int grow = bmPrev + wm * 64 + m * 16 + r16;
    float* Crow = C + (size_t)grow * N;
    #pragma unroll
    for (int n = 0; n < 4; ++n) {
      const int gcol = bn + wn * 64 + n * 16 + ks * 4;
      float4 o;
      o.x = pacc[m][n][0] + biasv[n].x;
      o.y = pacc[m][n][1] + biasv[n].y;
      o.z = pacc[m][n][2] + biasv[n].z;
      o.w = pacc[m][n][3] + biasv[n].w;
      *(float4*)(Crow + gcol) = o;
    }
  }
}

// ---------------------------------------------------------------------------
// Small GEMM, 64x128 tile, BK=32, 256 thr, swapped-operand float4 epilogue.
// GATHER: A rows = bf16(Afp[tok[row]]), K must be 512.
// ---------------------------------------------------------------------------
template <bool GATHER>
__global__ __launch_bounds__(256) void gemm64(
    const float* __restrict__ Afp, const int* __restrict__ tok,
    const u16* __restrict__ A, const u16* __restrict__ B,
    const float* __restrict__ bias, int blvl, float bscale,
    float* __restrict__ C, u16* __restrict__ Cb,
    int M, int N, int K)
{
  __shared__ u16 ldsA[64 * 32];    // 4 KB
  __shared__ u16 ldsB[128 * 32];   // 8 KB
  const int t = threadIdx.x, w = t >> 6, lane = t & 63;
  const int r16 = lane & 15, ks = lane >> 4;

  const int nb = gridDim.x * gridDim.y;
  const int lid = blockIdx.y * gridDim.x + blockIdx.x;
  const int chunk = nb >> 3;
  const int nlid = (lid & 7) * chunk + (lid >> 3);
  const int bm = (nlid % gridDim.x) * 64;
  const int bn = (nlid / gridDim.x) * 128;

  const int srow = t >> 2, sslot = t & 3;

  f32x4 acc[4][2];
  #pragma unroll
  for (int m = 0; m < 4; ++m)
    #pragma unroll
    for (int n = 0; n < 2; ++n) {
      f32x4 z = {0.f, 0.f, 0.f, 0.f};
      acc[m][n] = z;
    }

  for (int k0 = 0; k0 < K; k0 += 32) {
    if (k0) __syncthreads();
    {
      const int row = srow;                       // 0..63
      const int sl = sslot ^ ((row >> 1) & 3);
      if constexpr (GATHER) {
        const float* src = Afp + (size_t)tok[bm + row] * 512 + k0 + sl * 8;
        const float4 a0 = *(const float4*)src;
        const float4 a1 = *(const float4*)(src + 4);
        bf16x8 v;
        v[0] = (short)f2b(a0.x); v[1] = (short)f2b(a0.y);
        v[2] = (short)f2b(a0.z); v[3] = (short)f2b(a0.w);
        v[4] = (short)f2b(a1.x); v[5] = (short)f2b(a1.y);
        v[6] = (short)f2b(a1.z); v[7] = (short)f2b(a1.w);
        *(bf16x8*)(ldsA + t * 8) = v;
      } else {
        gload16(A + (size_t)(bm + row) * K + k0 + sl * 8, ldsA + w * 512);
      }
    }
    #pragma unroll
    for (int i = 0; i < 2; ++i) {
      const int row = i * 64 + srow;
      const int sl = sslot ^ ((row >> 1) & 3);
      gload16(B + (size_t)(bn + row) * K + k0 + sl * 8,
              ldsB + i * 2048 + w * 512);
    }
    __syncthreads();

    bf16x8 af[4], bfr[2];
    #pragma unroll
    for (int m = 0; m < 4; ++m) {
      const int row = m * 16 + r16;
      af[m] = *(const bf16x8*)(ldsA + row * 32 + ((ks ^ ((row >> 1) & 3)) << 3));
    }
    #pragma unroll
    for (int n = 0; n < 2; ++n) {
      const int row = w * 32 + n * 16 + r16;
      bfr[n] = *(const bf16x8*)(ldsB + row * 32 + ((ks ^ ((row >> 1) & 3)) << 3));
    }
    #pragma unroll
    for (int m = 0; m < 4; ++m)
      #pragma unroll
      for (int n = 0; n < 2; ++n)
        acc[m][n] = __builtin_amdgcn_mfma_f32_16x16x32_bf16(bfr[n], af[m], acc[m][n], 0, 0, 0);
  }

  const float* be = bias + (size_t)(bm >> 12) * blvl;
  #pragma unroll
  for (int m = 0; m < 4; ++m) {
    const int grow = bm + m * 16 + r16;
    #pragma unroll
    for (int n = 0; n < 2; ++n) {
      const int gcol = bn + w * 32 + n * 16 + ks * 4;
      const float4 bv = *(const float4*)(be + gcol);
      float4 o;
      o.x = acc[m][n][0] + bv.x * bscale;
      o.y = acc[m][n][1] + bv.y * bscale;
      o.z = acc[m][n][2] + bv.z * bscale;
      o.w = acc[m][n][3] + bv.w * bscale;
      const size_t idx = (size_t)grow * N + gcol;
      *(float4*)(C + idx) = o;
      if (Cb) {
        ushort4 ob = { f2b(o.x), f2b(o.y), f2b(o.z), f2b(o.w) };
        *(ushort4*)(Cb + idx) = ob;
      }
    }
  }
}

// ---------------------------------------------------------------------------
// bf16 MFMA GEMM, 128x128 tile, BK=32, swapped-operand epilogue (S3+POOL).
// ---------------------------------------------------------------------------
__global__ __launch_bounds__(256) void gemm_pool(
    const u16* __restrict__ A, const u16* __restrict__ B,
    const float* __restrict__ bias, float bscale,
    const float* __restrict__ h0f, const float* __restrict__ S1f,
    const float* __restrict__ S2f, const float* __restrict__ psum,
    u16* __restrict__ P,
    int M, int N, int K)
{
  __shared__ u16 ldsA[128 * 32];
  __shared__ u16 ldsB[128 * 32];
  const int t = threadIdx.x;
  const int w = t >> 6;
  const int lane = t & 63;
  const int wr = w >> 1, wc = w & 1;

  const int nb = gridDim.x * gridDim.y;
  const int lid = blockIdx.y * gridDim.x + blockIdx.x;
  const int chunk = nb >> 3;
  const int nlid = (lid & 7) * chunk + (lid >> 3);
  const int bx = nlid % gridDim.x, by = nlid / gridDim.x;

  const int bm = bx * 128, bn = by * 128;
  const int r16 = lane & 15, ks = lane >> 4;
  const int srow = t >> 2, sslot = t & 3;

  f32x4 acc[4][4];
  #pragma unroll
  for (int m = 0; m < 4; ++m)
    #pragma unroll
    for (int n = 0; n < 4; ++n) {
      f32x4 z = {0.f, 0.f, 0.f, 0.f};
      acc[m][n] = z;
    }

  for (int k0 = 0; k0 < K; k0 += 32) {
    if (k0) __syncthreads();
    #pragma unroll
    for (int i = 0; i < 2; ++i) {
      const int row = srow + i * 64;
      const int sl = sslot ^ ((row >> 1) & 3);
      gload16(A + (size_t)(bm + row) * K + k0 + sl * 8,
              ldsA + (i * 2048 + w * 512));
      gload16(B + (size_t)(bn + row) * K + k0 + sl * 8,
              ldsB + (i * 2048 + w * 512));
    }
    __syncthreads();

    bf16x8 af[4], bfr[4];
    #pragma unroll
    for (int m = 0; m < 4; ++m) {
      const int row = wr * 64 + m * 16 + r16;
      af[m] = *(const bf16x8*)(ldsA + row * 32 + ((ks ^ ((row >> 1) & 3)) << 3));
    }
    #pragma unroll
    for (int n = 0; n < 4; ++n) {
      const int row = wc * 64 + n * 16 + r16;
      bfr[n] = *(const bf16x8*)(ldsB + row * 32 + ((ks ^ ((row >> 1) & 3)) << 3));
    }
    #pragma unroll
    for (int m = 0; m < 4; ++m)
      #pragma unroll
      for (int n = 0; n < 4; ++n)
        acc[m][n] = __builtin_amdgcn_mfma_f32_16x16x32_bf16(bfr[n], af[m], acc[m][n], 0, 0, 0);
  }

  const float a0 = (psum[0] * (1.f / 4096.f) >= 0.5f) ? 1.f : 0.f;
  const float a1 = a0 * ((psum[1] * (1.f / 4096.f) >= 0.5f) ? 1.f : 0.f);
  const float a2 = a1 * ((psum[2] * (1.f / 4096.f) >= 0.5f) ? 1.f : 0.f);
  const float cnt = 1.f + a0 * 2.f + a1 * 4.f + a2 * 8.f;
  const float inv = 1.f / fmaxf(cnt, 1e-8f);

  #pragma unroll
  for (int m = 0; m < 4; ++m) {
    const int grow = bm + wr * 64 + m * 16 + r16;
    #pragma unroll
    for (int n = 0; n < 4; ++n) {
      const int gcol = bn + wc * 64 + n * 16 + ks * 4;
      const float4 bv = *(const float4*)(bias + gcol);
      float4 o;
      o.x = acc[m][n][0] + bv.x * bscale;
      o.y = acc[m][n][1] + bv.y * bscale;
      o.z = acc[m][n][2] + bv.z * bscale;
      o.w = acc[m][n][3] + bv.w * bscale;
      const size_t idx = (size_t)grow * N + gcol;
      const float4 h = *(const float4*)(h0f + idx);
      const float4 s1 = *(const float4*)(S1f + idx);
      const float4 s2 = *(const float4*)(S2f + idx);
      ushort4 ob;
      ob.x = f2b((h.x + a0 * s1.x + a1 * s2.x + a2 * o.x) * inv);
      ob.y = f2b((h.y + a0 * s1.y + a1 * s2.y + a2 * o.y) * inv);
      ob.z = f2b((h.z + a0 * s1.z + a1 * s2.z + a2 * o.z) * inv);
      ob.w = f2b((h.w + a0 * s1.w + a1 * s2.w + a2 * o.w) * inv);
      *(ushort4*)(P + idx) = ob;
    }
  }
}

// ---------------------------------------------------------------------------
// fused weight prep + out_w conversion, role-dispatched (grid 16676)
// ---------------------------------------------------------------------------
__global__ __launch_bounds__(256) void prep_misc(
    const float* __restrict__ cf_w, const float* __restrict__ cf_b,
    const float* __restrict__ sib, const float* __restrict__ proj_w,
    const float* __restrict__ f1w, const float* __restrict__ f1b,
    const float* __restrict__ f2w, const float* __restrict__ pde,
    const float* __restrict__ out_w,
    u16* __restrict__ wsum_b, u16* __restrict__ projw_b,
    u16* __restrict__ f1w512b, u16* __restrict__ f2wb,
    float* __restrict__ cvec, float* __restrict__ psum,
    float* __restrict__ y1bias, u16* __restrict__ outw_b)
{
  const int b = blockIdx.x, t = threadIdx.x;
  if (b >= 676) {
    const int idx = (b - 676) * 256 + t;
    const float4 v = ((const float4*)out_w)[idx];
    ushort4 o = { f2b(v.x), f2b(v.y), f2b(v.z), f2b(v.w) };
    ((ushort4*)outw_b)[idx] = o;
  } else if (b < 256) {
    const int idx = b * 256 + t;
    const float4 a = ((const float4*)cf_w)[idx];
    const float4 c = ((const float4*)(cf_w + 262144))[idx];
    ushort4 o = { f2b(a.x + c.x), f2b(a.y + c.y), f2b(a.z + c.z), f2b(a.w + c.w) };
    ((ushort4*)wsum_b)[idx] = o;
  } else if (b < 512) {
    const int idx = (b - 256) * 256 + t;
    const float4 v = ((const float4*)proj_w)[idx];
    ushort4 o = { f2b(v.x), f2b(v.y), f2b(v.z), f2b(v.w) };
    ((ushort4*)projw_b)[idx] = o;
  } else if (b < 640) {
    const int fi = (b - 512) * 256 + t;
    const int row = fi >> 7, c4 = fi & 127;
    const float4 v = *(const float4*)(f1w + (size_t)row * 640 + c4 * 4);
    ushort4 o = { f2b(v.x), f2b(v.y), f2b(v.z), f2b(v.w) };
    ((ushort4*)f1w512b)[row * 128 + c4] = o;
  } else if (b < 672) {
    const int idx = (b - 640) * 256 + t;
    const float4 v = ((const float4*)f2w)[idx];
    ushort4 o = { f2b(v.x), f2b(v.y), f2b(v.z), f2b(v.w) };
    ((ushort4*)f2wb)[idx] = o;
  } else if (b < 675) {
    const int l = b - 672, j = t;
    const float* wrow = f1w + (size_t)j * 640 + 512;
    const float* p = pde + l * 128;
    float s = f1b[j];
    #pragma unroll 4
    for (int k = 0; k < 128; ++k) s += wrow[k] * p[k];
    y1bias[l * 256 + j] = s;
  } else {
    cvec[t]       = cf_b[t]       + cf_b[512 + t] + SIB_SCALE_F * (sib[t]       + sib[512 + t]);
    cvec[256 + t] = cf_b[256 + t] + cf_b[768 + t] + SIB_SCALE_F * (sib[256 + t] + sib[768 + t]);
    if (t < 3) psum[t] = 0.f;
  }
}

// ---------------------------------------------------------------------------
// batched policy input over 3 levels: X[g] = bf16(LN(S_l/2^l + 0.01*dep_l))
// ---------------------------------------------------------------------------
__global__ __launch_bounds__(256) void mean_ln_concat_b(
    const float* __restrict__ S0, const float* __restrict__ S1,
    const float* __restrict__ S2,
    const float* __restrict__ dep,
    const float* __restrict__ g, const float* __restrict__ b,
    u16* __restrict__ X)
{
  const int wid = threadIdx.x >> 6, lane = threadIdx.x & 63;
  const int gr = blockIdx.x * 4 + wid;          // 0..12287
  const int l = gr >> 12, n = gr & 4095;
  const float* Sr = (l == 0 ? S0 : l == 1 ? S1 : S2) + (size_t)n * 512;
  const float invM = (l == 0 ? 1.f : l == 1 ? 0.5f : 0.25f);
  const float* depl = dep + 512 * l;
  const int c0 = lane * 8;
  float x[8];
  float s = 0.f, sq = 0.f;
  #pragma unroll
  for (int i = 0; i < 8; ++i) {
    const float v = Sr[c0 + i] * invM + 0.01f * depl[c0 + i];
    x[i] = v; s += v; sq += v * v;
  }
  s = wred(s); sq = wred(sq);
  const float mean = s * (1.f / 512.f);
  const float var = sq * (1.f / 512.f) - mean * mean;
  const float rs = rsqrtf(var + 1e-5f);
  ushort4 o0, o1;
  o0.x = f2b((x[0] - mean) * rs * g[c0 + 0] + b[c0 + 0]);
  o0.y = f2b((x[1] - mean) * rs * g[c0 + 1] + b[c0 + 1]);
  o0.z = f2b((x[2] - mean) * rs * g[c0 + 2] + b[c0 + 2]);
  o0.w = f2b((x[3] - mean) * rs * g[c0 + 3] + b[c0 + 3]);
  o1.x = f2b((x[4] - mean) * rs * g[c0 + 4] + b[c0 + 4]);
  o1.y = f2b((x[5] - mean) * rs * g[c0 + 5] + b[c0 + 5]);
  o1.z = f2b((x[6] - mean) * rs * g[c0 + 6] + b[c0 + 6]);
  o1.w = f2b((x[7] - mean) * rs * g[c0 + 7] + b[c0 + 7]);
  ushort4* Xr = (ushort4*)(X + (size_t)gr * 512);
  Xr[lane * 2]     = o0;
  Xr[lane * 2 + 1] = o1;
}

// LN + relu over 256 cols, fp32 in -> bf16 out
__global__ __launch_bounds__(256) void ln_relu_b256(
    const float* __restrict__ X, const float* __restrict__ g,
    const float* __restrict__ b, u16* __restrict__ O)
{
  const int wid = threadIdx.x >> 6, lane = threadIdx.x & 63;
  const int n = blockIdx.x * 4 + wid;
  const float* Xr = X + (size_t)n * 256;
  float x[4];
  float s = 0.f, sq = 0.f;
  #pragma unroll
  for (int i = 0; i < 4; ++i) {
    x[i] = Xr[lane * 4 + i]; s += x[i]; sq += x[i] * x[i];
  }
  s = wred(s); sq = wred(sq);
  const float mean = s * (1.f / 256.f);
  const float var = sq * (1.f / 256.f) - mean * mean;
  const float rs = rsqrtf(var + 1e-5f);
  ushort4 o;
  o.x = f2b(fmaxf((x[0] - mean) * rs * g[lane * 4 + 0] + b[lane * 4 + 0], 0.f));
  o.y = f2b(fmaxf((x[1] - mean) * rs * g[lane * 4 + 1] + b[lane * 4 + 1], 0.f));
  o.z = f2b(fmaxf((x[2] - mean) * rs * g[lane * 4 + 2] + b[lane * 4 + 2], 0.f));
  o.w = f2b(fmaxf((x[3] - mean) * rs * g[lane * 4 + 3] + b[lane * 4 + 3], 0.f));
  ((ushort4*)(O + (size_t)n * 256))[lane] = o;
}

// fused: LN(128) + relu + dot(pow_w) + sigmoid + clip + per-level atomicAdd
__global__ __launch_bounds__(256) void ln_policy128(
    const float* __restrict__ Y2, const float* __restrict__ g,
    const float* __restrict__ b, const float* __restrict__ pw,
    const float* __restrict__ pb, float* __restrict__ psum)
{
  __shared__ float part[4];
  const int wid = threadIdx.x >> 6, lane = threadIdx.x & 63;
  const int gr = blockIdx.x * 4 + wid;
  const float* Xr = Y2 + (size_t)gr * 128;
  float x[2];
  float s = 0.f, sq = 0.f;
  #pragma unroll
  for (int i = 0; i < 2; ++i) {
    x[i] = Xr[lane * 2 + i]; s += x[i]; sq += x[i] * x[i];
  }
  s = wred(s); sq = wred(sq);
  const float mean = s * (1.f / 128.f);
  const float var = sq * (1.f / 128.f) - mean * mean;
  const float rs = rsqrtf(var + 1e-5f);
  float z = 0.f;
  #pragma unroll
  for (int i = 0; i < 2; ++i) {
    const int c = lane * 2 + i;
    const float v = fmaxf((x[i] - mean) * rs * g[c] + b[c], 0.f);
    z += v * pw[c];
  }
  z = wred(z);
  if (lane == 0) {
    const float p = 1.f / (1.f + expf(-(z + pb[0])));
    part[wid] = fminf(fmaxf(p, 1e-7f), 1.f - 1e-7f);
  }
  __syncthreads();
  if (threadIdx.x == 0)
    atomicAdd(psum + (gr >> 12), part[0] + part[1] + part[2] + part[3]);
}

// ---------------------------------------------------------------------------
extern "C" void kernel_launch(void* const* d_in, const int* in_sizes, int n_in,
                              void* d_out, int out_size, void* d_ws, size_t ws_size,
                              hipStream_t stream) {
  const int*   tok    = (const int*)  d_in[0];
  const float* emb    = (const float*)d_in[1];
  const float* proj_w = (const float*)d_in[2];
  const float* proj_b = (const float*)d_in[3];
  const float* cf_w   = (const float*)d_in[4];
  const float* cf_b   = (const float*)d_in[5];
  const float* in_g   = (const float*)d_in[6];
  const float* in_b   = (const float*)d_in[7];
  const float* pde    = (const float*)d_in[8];
  const float* f1w    = (const float*)d_in[9];
  const float* f1b    = (const float*)d_in[10];
  const float* n1g    = (const float*)d_in[11];
  const float* n1b    = (const float*)d_in[12];
  const float* f2w    = (const float*)d_in[13];
  const float* f2bias = (const float*)d_in[14];
  const float* n2g    = (const float*)d_in[15];
  const float* n2b    = (const float*)d_in[16];
  const float* pow_w  = (const float*)d_in[17];
  const float* pow_b  = (const float*)d_in[18];
  const float* sib    = (const float*)d_in[19];
  const float* dep    = (const float*)d_in[20];
  const float* out_w  = (const float*)d_in[21];
  const float* out_b  = (const float*)d_in[22];
  float* out = (float*)d_out;

  char* ws = (char*)d_ws;
  size_t off = 0;
  auto alloc = [&](size_t bytes) -> void* {
    void* p = ws + off;
    off += (bytes + 255) & ~(size_t)255;
    return p;
  };
  u16*   outw_b  = (u16*)  alloc((size_t)32000 * 512 * 2);
  u16*   projw_b = (u16*)  alloc((size_t)512 * 512 * 2);
  u16*   wsum_b  = (u16*)  alloc((size_t)512 * 512 * 2);
  u16*   f1w512b = (u16*)  alloc((size_t)256 * 512 * 2);
  u16*   f2wb    = (u16*)  alloc((size_t)128 * 256 * 2);
  float* h0f     = (float*)alloc((size_t)4096 * 512 * 4);
  u16*   h0b     = (u16*)  alloc((size_t)4096 * 512 * 2);
  float* S1f     = (float*)alloc((size_t)4096 * 512 * 4);
  u16*   S1b     = (u16*)  alloc((size_t)4096 * 512 * 2);
  float* S2f     = (float*)alloc((size_t)4096 * 512 * 4);
  u16*   S2b     = (u16*)  alloc((size_t)4096 * 512 * 2);
  u16*   X       = (u16*)  alloc((size_t)12288 * 512 * 2);
  float* Y1      = (float*)alloc((size_t)12288 * 256 * 4);
  u16*   Y1b     = (u16*)  alloc((size_t)12288 * 256 * 2);
  float* Y2      = (float*)alloc((size_t)12288 * 128 * 4);
  float* y1bias  = (float*)alloc(3 * 256 * 4);
  float* cvec    = (float*)alloc(512 * 4);
  float* psum    = (float*)alloc(256);
  u16*   poolb   = (u16*)  alloc((size_t)4096 * 512 * 2);

  prep_misc<<<16676, 256, 0, stream>>>(cf_w, cf_b, sib, proj_w, f1w, f1b, f2w,
                                       pde, out_w,
                                       wsum_b, projw_b, f1w512b, f2wb,
                                       cvec, psum, y1bias, outw_b);

  // h0 = emb[tok] @ proj_w^T + proj_b
  gemm64<true><<<dim3(64, 4), 256, 0, stream>>>(
      emb, tok, nullptr, projw_b, proj_b, 0, 1.f, h0f, h0b, 4096, 512, 512);
  // S1, S2
  gemm64<false><<<dim3(64, 4), 256, 0, stream>>>(
      nullptr, nullptr, h0b, wsum_b, cvec, 0, 1.f, S1f, S1b, 4096, 512, 512);
  gemm64<false><<<dim3(64, 4), 256, 0, stream>>>(
      nullptr, nullptr, S1b, wsum_b, cvec, 0, 2.f, S2f, S2b, 4096, 512, 512);

  // policy, 3 levels batched
  mean_ln_concat_b<<<3072, 256, 0, stream>>>(h0f, S1f, S2f, dep, in_g, in_b, X);
  gemm64<false><<<dim3(192, 2), 256, 0, stream>>>(
      nullptr, nullptr, X, f1w512b, y1bias, 256, 1.f, Y1, nullptr, 12288, 256, 512);
  ln_relu_b256<<<3072, 256, 0, stream>>>(Y1, n1g, n1b, Y1b);
  gemm64<false><<<dim3(192, 1), 256, 0, stream>>>(
      nullptr, nullptr, Y1b, f2wb, f2bias, 0, 1.f, Y2, nullptr, 12288, 128, 256);
  ln_policy128<<<3072, 256, 0, stream>>>(Y2, n2g, n2b, pow_w, pow_b, psum);

  // S3 GEMM fused with pooling (128^2, proven)
  gemm_pool<<<dim3(32, 4), 256, 0, stream>>>(
      S2b, wsum_b, cvec, 4.f, h0f, S1f, S2f, psum, poolb, 4096, 512, 512);

  // out = pooled @ out_w^T + out_b (4096 x 32000 x 512)
  // B-resident: one 128-col panel per block, staged once; A streams
  gemmV<<<250, 256, 0, stream>>>(poolb, outw_b, out_b, out, 4096, 32000, 512);
}

// Round 18
// 389.008 us; speedup vs baseline: 1.2025x; 1.0222x over previous
//
#include <hip/hip_runtime.h>

typedef unsigned short u16;
using bf16x8 = __attribute__((ext_vector_type(8))) short;
using f32x4  = __attribute__((ext_vector_type(4))) float;

#define SIB_SCALE_F 0.04419417382415922f   // 1/sqrt(512)

__device__ __forceinline__ u16 f2b(float f) {
  unsigned u = __builtin_bit_cast(unsigned, f);
  return (u16)((u + 0x7FFFu + ((u >> 16) & 1u)) >> 16);   // RNE
}

__device__ __forceinline__ float wred(float v) {
  #pragma unroll
  for (int m = 1; m < 64; m <<= 1) v += __shfl_xor(v, m);
  return v;
}

__device__ __forceinline__ void gload16(const void* g, void* l) {
  __builtin_amdgcn_global_load_lds(
      (const __attribute__((address_space(1))) unsigned int*)g,
      (__attribute__((address_space(3))) unsigned int*)l, 16, 0, 0);
}

// ---------------------------------------------------------------------------
// B-RESIDENT final GEMM "gemmV" (R18: 8 waves for 2 waves/SIMD).
// Block = one 128-col B panel staged into LDS ONCE (128KB), reused across
// all 32 m-tiles; A streams via 3-buffered 8KB tiles (BK=32, 1 gload16/thr).
// 512 thr = 8 waves (2m x 4n), wave-tile 64x32, acc 4x2 -- 2 waves/SIMD so
// one wave's MFMA hides the other's LDS reads/barriers (R17 ran 1 wave/SIMD
// and was latency-bound at ~290us despite tiny fetch).
// Order-robust sync: uniform entry vmcnt(1) (in-order queue: drains A(g) and
// any seam stores, leaves A(g+1)); vmcnt(0) at final kt.  Seam stores
// (regular float4, 8/thread) at kt0 BEFORE stageA, pinned by sched_barrier.
// m-tile order staggered per block.  grid=250.  M==4096,K==512 hardcoded.
// ---------------------------------------------------------------------------
__global__ __launch_bounds__(512, 1) void gemmV(
    const u16* __restrict__ A, const u16* __restrict__ B,
    const float* __restrict__ bias,
    float* __restrict__ C, int M, int N, int K)
{
  __shared__ u16 lds[77824];   // B: [0,65536) ; A: [65536,77824) = 3 x 4096 u16
  const int t = threadIdx.x, w = t >> 6, lane = t & 63;
  const int wm = w >> 2, wn = w & 3;          // 2m x 4n, wave-tile 64x32
  const int r16 = lane & 15, ks = lane >> 4;
  const int bn = blockIdx.x * 128;
  const int stag = blockIdx.x & 31;

  // ---- stage the full B panel: wave w stages col (i*8+w), pre-swizzled ----
  #pragma unroll 4
  for (int i = 0; i < 16; ++i) {
    const int c = i * 8 + w;
    const int ksrc = (lane & ~7) | ((lane & 7) ^ (c & 7));
    gload16(B + (size_t)(bn + c) * 512 + ksrc * 8, lds + c * 512);
  }

  // A tile stage: 128 rows x 32 K (8 KB), 1 gload16/thread
  auto stageA = [&](int bmT, int kt, int buf) {
    u16* dst = lds + 65536 + buf * 4096;
    const int r = w * 16 + (lane >> 2);
    const int s = (lane & 3) ^ (r & 3);
    gload16(A + (size_t)(bmT + r) * 512 + kt * 32 + s * 8, dst + w * 512);
  };

  float4 biasv[2];
  #pragma unroll
  for (int n = 0; n < 2; ++n)
    biasv[n] = *(const float4*)(bias + bn + wn * 32 + n * 16 + ks * 4);

  f32x4 acc[4][2], pacc[4][2];
  #pragma unroll
  for (int m = 0; m < 4; ++m)
    #pragma unroll
    for (int n = 0; n < 2; ++n) {
      f32x4 z = {0.f, 0.f, 0.f, 0.f};
      acc[m][n] = z; pacc[m][n] = z;
    }
  int bmPrev = 0;

  // prologue: A(0), A(1); vmcnt(1) drains B + A(0), leaves A(1)
  {
    const int bm0 = (stag & 31) * 128;
    stageA(bm0, 0, 0);
    stageA(bm0, 1, 1);
    asm volatile("s_waitcnt vmcnt(1)" ::: "memory");
    __builtin_amdgcn_sched_barrier(0);
  }

  int bufR = 0;   // g % 3
  for (int mt = 0; mt < 32; ++mt) {
    const int bm  = ((mt + stag) & 31) * 128;
    const int bmN = ((mt + 1 + stag) & 31) * 128;

    #pragma unroll
    for (int kt = 0; kt < 16; ++kt) {
      const int g = mt * 16 + kt;
      if (g > 0) {
        if (g == 511) asm volatile("s_waitcnt vmcnt(0)" ::: "memory");
        else          asm volatile("s_waitcnt vmcnt(1)" ::: "memory");
        __builtin_amdgcn_sched_barrier(0);
      }
      __builtin_amdgcn_s_barrier();

      const u16* Ab = lds + 65536 + bufR * 4096;
      bf16x8 af[4], bfr[2];
      #pragma unroll
      for (int m = 0; m < 4; ++m) {
        const int row = wm * 64 + m * 16 + r16;
        af[m] = *(const bf16x8*)(Ab + row * 32 + ((ks ^ (row & 3)) << 3));
      }
      #pragma unroll
      for (int n = 0; n < 2; ++n) {
        const int col = wn * 32 + n * 16 + r16;
        bfr[n] = *(const bf16x8*)(lds + col * 512 + (kt >> 1) * 64 +
                                  ((((kt & 1) * 4 + ks) ^ (col & 7)) << 3));
      }

      // ---- seam stores (previous m-tile), BEFORE the A stage, pinned ----
      if (kt == 0 && mt > 0) {
        __builtin_amdgcn_sched_barrier(0);
        #pragma unroll
        for (int m = 0; m < 4; ++m) {
          const int grow = bmPrev + wm * 64 + m * 16 + r16;
          float* Crow = C + (size_t)grow * N;
          #pragma unroll
          for (int n = 0; n < 2; ++n) {
            const int gcol = bn + wn * 32 + n * 16 + ks * 4;
            float4 o;
            o.x = pacc[m][n][0] + biasv[n].x;
            o.y = pacc[m][n][1] + biasv[n].y;
            o.z = pacc[m][n][2] + biasv[n].z;
            o.w = pacc[m][n][3] + biasv[n].w;
            *(float4*)(Crow + gcol) = o;
          }
        }
        __builtin_amdgcn_sched_barrier(0);
      }

      // ---- stage A(g+2) ----
      if (g + 2 < 512) {
        const int kt2 = kt + 2;
        const int bm2 = (kt2 < 16) ? bm : bmN;
        stageA(bm2, kt2 & 15, (bufR + 2) % 3);
      }

      asm volatile("s_waitcnt lgkmcnt(0)" ::: "memory");
      __builtin_amdgcn_sched_barrier(0);
      __builtin_amdgcn_s_setprio(1);
      #pragma unroll
      for (int m = 0; m < 4; ++m)
        #pragma unroll
        for (int n = 0; n < 2; ++n)
          acc[m][n] = __builtin_amdgcn_mfma_f32_16x16x32_bf16(bfr[n], af[m], acc[m][n], 0, 0, 0);
      __builtin_amdgcn_s_setprio(0);

      if (kt == 15) {
        bmPrev = bm;
        #pragma unroll
        for (int m = 0; m < 4; ++m)
          #pragma unroll
          for (int n = 0; n < 2; ++n) {
            pacc[m][n] = acc[m][n];
            f32x4 z = {0.f, 0.f, 0.f, 0.f};
            acc[m][n] = z;
          }
      }
      bufR = (bufR + 1) % 3;
    }
  }

  // final m-tile's stores
  #pragma unroll
  for (int m = 0; m < 4; ++m) {
    const int grow = bmPrev + wm * 64 + m * 16 + r16;
    float* Crow = C + (size_t)grow * N;
    #pragma unroll
    for (int n = 0; n < 2; ++n) {
      const int gcol = bn + wn * 32 + n * 16 + ks * 4;
      float4 o;
      o.x = pacc[m][n][0] + biasv[n].x;
      o.y = pacc[m][n][1] + biasv[n].y;
      o.z = pacc[m][n][2] + biasv[n].z;
      o.w = pacc[m][n][3] + biasv[n].w;
      *(float4*)(Crow + gcol) = o;
    }
  }
}

// ---------------------------------------------------------------------------
// Small GEMM, 64x128 tile, BK=32, 256 thr, swapped-operand float4 epilogue.
// GATHER: A rows = bf16(Afp[tok[row]]), K must be 512.
// ---------------------------------------------------------------------------
template <bool GATHER>
__global__ __launch_bounds__(256) void gemm64(
    const float* __restrict__ Afp, const int* __restrict__ tok,
    const u16* __restrict__ A, const u16* __restrict__ B,
    const float* __restrict__ bias, int blvl, float bscale,
    float* __restrict__ C, u16* __restrict__ Cb,
    int M, int N, int K)
{
  __shared__ u16 ldsA[64 * 32];    // 4 KB
  __shared__ u16 ldsB[128 * 32];   // 8 KB
  const int t = threadIdx.x, w = t >> 6, lane = t & 63;
  const int r16 = lane & 15, ks = lane >> 4;

  const int nb = gridDim.x * gridDim.y;
  const int lid = blockIdx.y * gridDim.x + blockIdx.x;
  const int chunk = nb >> 3;
  const int nlid = (lid & 7) * chunk + (lid >> 3);
  const int bm = (nlid % gridDim.x) * 64;
  const int bn = (nlid / gridDim.x) * 128;

  const int srow = t >> 2, sslot = t & 3;

  f32x4 acc[4][2];
  #pragma unroll
  for (int m = 0; m < 4; ++m)
    #pragma unroll
    for (int n = 0; n < 2; ++n) {
      f32x4 z = {0.f, 0.f, 0.f, 0.f};
      acc[m][n] = z;
    }

  for (int k0 = 0; k0 < K; k0 += 32) {
    if (k0) __syncthreads();
    {
      const int row = srow;                       // 0..63
      const int sl = sslot ^ ((row >> 1) & 3);
      if constexpr (GATHER) {
        const float* src = Afp + (size_t)tok[bm + row] * 512 + k0 + sl * 8;
        const float4 a0 = *(const float4*)src;
        const float4 a1 = *(const float4*)(src + 4);
        bf16x8 v;
        v[0] = (short)f2b(a0.x); v[1] = (short)f2b(a0.y);
        v[2] = (short)f2b(a0.z); v[3] = (short)f2b(a0.w);
        v[4] = (short)f2b(a1.x); v[5] = (short)f2b(a1.y);
        v[6] = (short)f2b(a1.z); v[7] = (short)f2b(a1.w);
        *(bf16x8*)(ldsA + t * 8) = v;
      } else {
        gload16(A + (size_t)(bm + row) * K + k0 + sl * 8, ldsA + w * 512);
      }
    }
    #pragma unroll
    for (int i = 0; i < 2; ++i) {
      const int row = i * 64 + srow;
      const int sl = sslot ^ ((row >> 1) & 3);
      gload16(B + (size_t)(bn + row) * K + k0 + sl * 8,
              ldsB + i * 2048 + w * 512);
    }
    __syncthreads();

    bf16x8 af[4], bfr[2];
    #pragma unroll
    for (int m = 0; m < 4; ++m) {
      const int row = m * 16 + r16;
      af[m] = *(const bf16x8*)(ldsA + row * 32 + ((ks ^ ((row >> 1) & 3)) << 3));
    }
    #pragma unroll
    for (int n = 0; n < 2; ++n) {
      const int row = w * 32 + n * 16 + r16;
      bfr[n] = *(const bf16x8*)(ldsB + row * 32 + ((ks ^ ((row >> 1) & 3)) << 3));
    }
    #pragma unroll
    for (int m = 0; m < 4; ++m)
      #pragma unroll
      for (int n = 0; n < 2; ++n)
        acc[m][n] = __builtin_amdgcn_mfma_f32_16x16x32_bf16(bfr[n], af[m], acc[m][n], 0, 0, 0);
  }

  const float* be = bias + (size_t)(bm >> 12) * blvl;
  #pragma unroll
  for (int m = 0; m < 4; ++m) {
    const int grow = bm + m * 16 + r16;
    #pragma unroll
    for (int n = 0; n < 2; ++n) {
      const int gcol = bn + w * 32 + n * 16 + ks * 4;
      const float4 bv = *(const float4*)(be + gcol);
      float4 o;
      o.x = acc[m][n][0] + bv.x * bscale;
      o.y = acc[m][n][1] + bv.y * bscale;
      o.z = acc[m][n][2] + bv.z * bscale;
      o.w = acc[m][n][3] + bv.w * bscale;
      const size_t idx = (size_t)grow * N + gcol;
      *(float4*)(C + idx) = o;
      if (Cb) {
        ushort4 ob = { f2b(o.x), f2b(o.y), f2b(o.z), f2b(o.w) };
        *(ushort4*)(Cb + idx) = ob;
      }
    }
  }
}

// ---------------------------------------------------------------------------
// bf16 MFMA GEMM, 128x128 tile, BK=32, swapped-operand epilogue (S3+POOL).
// ---------------------------------------------------------------------------
__global__ __launch_bounds__(256) void gemm_pool(
    const u16* __restrict__ A, const u16* __restrict__ B,
    const float* __restrict__ bias, float bscale,
    const float* __restrict__ h0f, const float* __restrict__ S1f,
    const float* __restrict__ S2f, const float* __restrict__ psum,
    u16* __restrict__ P,
    int M, int N, int K)
{
  __shared__ u16 ldsA[128 * 32];
  __shared__ u16 ldsB[128 * 32];
  const int t = threadIdx.x;
  const int w = t >> 6;
  const int lane = t & 63;
  const int wr = w >> 1, wc = w & 1;

  const int nb = gridDim.x * gridDim.y;
  const int lid = blockIdx.y * gridDim.x + blockIdx.x;
  const int chunk = nb >> 3;
  const int nlid = (lid & 7) * chunk + (lid >> 3);
  const int bx = nlid % gridDim.x, by = nlid / gridDim.x;

  const int bm = bx * 128, bn = by * 128;
  const int r16 = lane & 15, ks = lane >> 4;
  const int srow = t >> 2, sslot = t & 3;

  f32x4 acc[4][4];
  #pragma unroll
  for (int m = 0; m < 4; ++m)
    #pragma unroll
    for (int n = 0; n < 4; ++n) {
      f32x4 z = {0.f, 0.f, 0.f, 0.f};
      acc[m][n] = z;
    }

  for (int k0 = 0; k0 < K; k0 += 32) {
    if (k0) __syncthreads();
    #pragma unroll
    for (int i = 0; i < 2; ++i) {
      const int row = srow + i * 64;
      const int sl = sslot ^ ((row >> 1) & 3);
      gload16(A + (size_t)(bm + row) * K + k0 + sl * 8,
              ldsA + (i * 2048 + w * 512));
      gload16(B + (size_t)(bn + row) * K + k0 + sl * 8,
              ldsB + (i * 2048 + w * 512));
    }
    __syncthreads();

    bf16x8 af[4], bfr[4];
    #pragma unroll
    for (int m = 0; m < 4; ++m) {
      const int row = wr * 64 + m * 16 + r16;
      af[m] = *(const bf16x8*)(ldsA + row * 32 + ((ks ^ ((row >> 1) & 3)) << 3));
    }
    #pragma unroll
    for (int n = 0; n < 4; ++n) {
      const int row = wc * 64 + n * 16 + r16;
      bfr[n] = *(const bf16x8*)(ldsB + row * 32 + ((ks ^ ((row >> 1) & 3)) << 3));
    }
    #pragma unroll
    for (int m = 0; m < 4; ++m)
      #pragma unroll
      for (int n = 0; n < 4; ++n)
        acc[m][n] = __builtin_amdgcn_mfma_f32_16x16x32_bf16(bfr[n], af[m], acc[m][n], 0, 0, 0);
  }

  const float a0 = (psum[0] * (1.f / 4096.f) >= 0.5f) ? 1.f : 0.f;
  const float a1 = a0 * ((psum[1] * (1.f / 4096.f) >= 0.5f) ? 1.f : 0.f);
  const float a2 = a1 * ((psum[2] * (1.f / 4096.f) >= 0.5f) ? 1.f : 0.f);
  const float cnt = 1.f + a0 * 2.f + a1 * 4.f + a2 * 8.f;
  const float inv = 1.f / fmaxf(cnt, 1e-8f);

  #pragma unroll
  for (int m = 0; m < 4; ++m) {
    const int grow = bm + wr * 64 + m * 16 + r16;
    #pragma unroll
    for (int n = 0; n < 4; ++n) {
      const int gcol = bn + wc * 64 + n * 16 + ks * 4;
      const float4 bv = *(const float4*)(bias + gcol);
      float4 o;
      o.x = acc[m][n][0] + bv.x * bscale;
      o.y = acc[m][n][1] + bv.y * bscale;
      o.z = acc[m][n][2] + bv.z * bscale;
      o.w = acc[m][n][3] + bv.w * bscale;
      const size_t idx = (size_t)grow * N + gcol;
      const float4 h = *(const float4*)(h0f + idx);
      const float4 s1 = *(const float4*)(S1f + idx);
      const float4 s2 = *(const float4*)(S2f + idx);
      ushort4 ob;
      ob.x = f2b((h.x + a0 * s1.x + a1 * s2.x + a2 * o.x) * inv);
      ob.y = f2b((h.y + a0 * s1.y + a1 * s2.y + a2 * o.y) * inv);
      ob.z = f2b((h.z + a0 * s1.z + a1 * s2.z + a2 * o.z) * inv);
      ob.w = f2b((h.w + a0 * s1.w + a1 * s2.w + a2 * o.w) * inv);
      *(ushort4*)(P + idx) = ob;
    }
  }
}

// ---------------------------------------------------------------------------
// fused weight prep + out_w conversion, role-dispatched (grid 16676)
// ---------------------------------------------------------------------------
__global__ __launch_bounds__(256) void prep_misc(
    const float* __restrict__ cf_w, const float* __restrict__ cf_b,
    const float* __restrict__ sib, const float* __restrict__ proj_w,
    const float* __restrict__ f1w, const float* __restrict__ f1b,
    const float* __restrict__ f2w, const float* __restrict__ pde,
    const float* __restrict__ out_w,
    u16* __restrict__ wsum_b, u16* __restrict__ projw_b,
    u16* __restrict__ f1w512b, u16* __restrict__ f2wb,
    float* __restrict__ cvec, float* __restrict__ psum,
    float* __restrict__ y1bias, u16* __restrict__ outw_b)
{
  const int b = blockIdx.x, t = threadIdx.x;
  if (b >= 676) {
    const int idx = (b - 676) * 256 + t;
    const float4 v = ((const float4*)out_w)[idx];
    ushort4 o = { f2b(v.x), f2b(v.y), f2b(v.z), f2b(v.w) };
    ((ushort4*)outw_b)[idx] = o;
  } else if (b < 256) {
    const int idx = b * 256 + t;
    const float4 a = ((const float4*)cf_w)[idx];
    const float4 c = ((const float4*)(cf_w + 262144))[idx];
    ushort4 o = { f2b(a.x + c.x), f2b(a.y + c.y), f2b(a.z + c.z), f2b(a.w + c.w) };
    ((ushort4*)wsum_b)[idx] = o;
  } else if (b < 512) {
    const int idx = (b - 256) * 256 + t;
    const float4 v = ((const float4*)proj_w)[idx];
    ushort4 o = { f2b(v.x), f2b(v.y), f2b(v.z), f2b(v.w) };
    ((ushort4*)projw_b)[idx] = o;
  } else if (b < 640) {
    const int fi = (b - 512) * 256 + t;
    const int row = fi >> 7, c4 = fi & 127;
    const float4 v = *(const float4*)(f1w + (size_t)row * 640 + c4 * 4);
    ushort4 o = { f2b(v.x), f2b(v.y), f2b(v.z), f2b(v.w) };
    ((ushort4*)f1w512b)[row * 128 + c4] = o;
  } else if (b < 672) {
    const int idx = (b - 640) * 256 + t;
    const float4 v = ((const float4*)f2w)[idx];
    ushort4 o = { f2b(v.x), f2b(v.y), f2b(v.z), f2b(v.w) };
    ((ushort4*)f2wb)[idx] = o;
  } else if (b < 675) {
    const int l = b - 672, j = t;
    const float* wrow = f1w + (size_t)j * 640 + 512;
    const float* p = pde + l * 128;
    float s = f1b[j];
    #pragma unroll 4
    for (int k = 0; k < 128; ++k) s += wrow[k] * p[k];
    y1bias[l * 256 + j] = s;
  } else {
    cvec[t]       = cf_b[t]       + cf_b[512 + t] + SIB_SCALE_F * (sib[t]       + sib[512 + t]);
    cvec[256 + t] = cf_b[256 + t] + cf_b[768 + t] + SIB_SCALE_F * (sib[256 + t] + sib[768 + t]);
    if (t < 3) psum[t] = 0.f;
  }
}

// ---------------------------------------------------------------------------
// batched policy input over 3 levels: X[g] = bf16(LN(S_l/2^l + 0.01*dep_l))
// ---------------------------------------------------------------------------
__global__ __launch_bounds__(256) void mean_ln_concat_b(
    const float* __restrict__ S0, const float* __restrict__ S1,
    const float* __restrict__ S2,
    const float* __restrict__ dep,
    const float* __restrict__ g, const float* __restrict__ b,
    u16* __restrict__ X)
{
  const int wid = threadIdx.x >> 6, lane = threadIdx.x & 63;
  const int gr = blockIdx.x * 4 + wid;          // 0..12287
  const int l = gr >> 12, n = gr & 4095;
  const float* Sr = (l == 0 ? S0 : l == 1 ? S1 : S2) + (size_t)n * 512;
  const float invM = (l == 0 ? 1.f : l == 1 ? 0.5f : 0.25f);
  const float* depl = dep + 512 * l;
  const int c0 = lane * 8;
  float x[8];
  float s = 0.f, sq = 0.f;
  #pragma unroll
  for (int i = 0; i < 8; ++i) {
    const float v = Sr[c0 + i] * invM + 0.01f * depl[c0 + i];
    x[i] = v; s += v; sq += v * v;
  }
  s = wred(s); sq = wred(sq);
  const float mean = s * (1.f / 512.f);
  const float var = sq * (1.f / 512.f) - mean * mean;
  const float rs = rsqrtf(var + 1e-5f);
  ushort4 o0, o1;
  o0.x = f2b((x[0] - mean) * rs * g[c0 + 0] + b[c0 + 0]);
  o0.y = f2b((x[1] - mean) * rs * g[c0 + 1] + b[c0 + 1]);
  o0.z = f2b((x[2] - mean) * rs * g[c0 + 2] + b[c0 + 2]);
  o0.w = f2b((x[3] - mean) * rs * g[c0 + 3] + b[c0 + 3]);
  o1.x = f2b((x[4] - mean) * rs * g[c0 + 4] + b[c0 + 4]);
  o1.y = f2b((x[5] - mean) * rs * g[c0 + 5] + b[c0 + 5]);
  o1.z = f2b((x[6] - mean) * rs * g[c0 + 6] + b[c0 + 6]);
  o1.w = f2b((x[7] - mean) * rs * g[c0 + 7] + b[c0 + 7]);
  ushort4* Xr = (ushort4*)(X + (size_t)gr * 512);
  Xr[lane * 2]     = o0;
  Xr[lane * 2 + 1] = o1;
}

// LN + relu over 256 cols, fp32 in -> bf16 out
__global__ __launch_bounds__(256) void ln_relu_b256(
    const float* __restrict__ X, const float* __restrict__ g,
    const float* __restrict__ b, u16* __restrict__ O)
{
  const int wid = threadIdx.x >> 6, lane = threadIdx.x & 63;
  const int n = blockIdx.x * 4 + wid;
  const float* Xr = X + (size_t)n * 256;
  float x[4];
  float s = 0.f, sq = 0.f;
  #pragma unroll
  for (int i = 0; i < 4; ++i) {
    x[i] = Xr[lane * 4 + i]; s += x[i]; sq += x[i] * x[i];
  }
  s = wred(s); sq = wred(sq);
  const float mean = s * (1.f / 256.f);
  const float var = sq * (1.f / 256.f) - mean * mean;
  const float rs = rsqrtf(var + 1e-5f);
  ushort4 o;
  o.x = f2b(fmaxf((x[0] - mean) * rs * g[lane * 4 + 0] + b[lane * 4 + 0], 0.f));
  o.y = f2b(fmaxf((x[1] - mean) * rs * g[lane * 4 + 1] + b[lane * 4 + 1], 0.f));
  o.z = f2b(fmaxf((x[2] - mean) * rs * g[lane * 4 + 2] + b[lane * 4 + 2], 0.f));
  o.w = f2b(fmaxf((x[3] - mean) * rs * g[lane * 4 + 3] + b[lane * 4 + 3], 0.f));
  ((ushort4*)(O + (size_t)n * 256))[lane] = o;
}

// fused: LN(128) + relu + dot(pow_w) + sigmoid + clip + per-level atomicAdd
__global__ __launch_bounds__(256) void ln_policy128(
    const float* __restrict__ Y2, const float* __restrict__ g,
    const float* __restrict__ b, const float* __restrict__ pw,
    const float* __restrict__ pb, float* __restrict__ psum)
{
  __shared__ float part[4];
  const int wid = threadIdx.x >> 6, lane = threadIdx.x & 63;
  const int gr = blockIdx.x * 4 + wid;
  const float* Xr = Y2 + (size_t)gr * 128;
  float x[2];
  float s = 0.f, sq = 0.f;
  #pragma unroll
  for (int i = 0; i < 2; ++i) {
    x[i] = Xr[lane * 2 + i]; s += x[i]; sq += x[i] * x[i];
  }
  s = wred(s); sq = wred(sq);
  const float mean = s * (1.f / 128.f);
  const float var = sq * (1.f / 128.f) - mean * mean;
  const float rs = rsqrtf(var + 1e-5f);
  float z = 0.f;
  #pragma unroll
  for (int i = 0; i < 2; ++i) {
    const int c = lane * 2 + i;
    const float v = fmaxf((x[i] - mean) * rs * g[c] + b[c], 0.f);
    z += v * pw[c];
  }
  z = wred(z);
  if (lane == 0) {
    const float p = 1.f / (1.f + expf(-(z + pb[0])));
    part[wid] = fminf(fmaxf(p, 1e-7f), 1.f - 1e-7f);
  }
  __syncthreads();
  if (threadIdx.x == 0)
    atomicAdd(psum + (gr >> 12), part[0] + part[1] + part[2] + part[3]);
}

// ---------------------------------------------------------------------------
extern "C" void kernel_launch(void* const* d_in, const int* in_sizes, int n_in,
                              void* d_out, int out_size, void* d_ws, size_t ws_size,
                              hipStream_t stream) {
  const int*   tok    = (const int*)  d_in[0];
  const float* emb    = (const float*)d_in[1];
  const float* proj_w = (const float*)d_in[2];
  const float* proj_b = (const float*)d_in[3];
  const float* cf_w   = (const float*)d_in[4];
  const float* cf_b   = (const float*)d_in[5];
  const float* in_g   = (const float*)d_in[6];
  const float* in_b   = (const float*)d_in[7];
  const float* pde    = (const float*)d_in[8];
  const float* f1w    = (const float*)d_in[9];
  const float* f1b    = (const float*)d_in[10];
  const float* n1g    = (const float*)d_in[11];
  const float* n1b    = (const float*)d_in[12];
  const float* f2w    = (const float*)d_in[13];
  const float* f2bias = (const float*)d_in[14];
  const float* n2g    = (const float*)d_in[15];
  const float* n2b    = (const float*)d_in[16];
  const float* pow_w  = (const float*)d_in[17];
  const float* pow_b  = (const float*)d_in[18];
  const float* sib    = (const float*)d_in[19];
  const float* dep    = (const float*)d_in[20];
  const float* out_w  = (const float*)d_in[21];
  const float* out_b  = (const float*)d_in[22];
  float* out = (float*)d_out;

  char* ws = (char*)d_ws;
  size_t off = 0;
  auto alloc = [&](size_t bytes) -> void* {
    void* p = ws + off;
    off += (bytes + 255) & ~(size_t)255;
    return p;
  };
  u16*   outw_b  = (u16*)  alloc((size_t)32000 * 512 * 2);
  u16*   projw_b = (u16*)  alloc((size_t)512 * 512 * 2);
  u16*   wsum_b  = (u16*)  alloc((size_t)512 * 512 * 2);
  u16*   f1w512b = (u16*)  alloc((size_t)256 * 512 * 2);
  u16*   f2wb    = (u16*)  alloc((size_t)128 * 256 * 2);
  float* h0f     = (float*)alloc((size_t)4096 * 512 * 4);
  u16*   h0b     = (u16*)  alloc((size_t)4096 * 512 * 2);
  float* S1f     = (float*)alloc((size_t)4096 * 512 * 4);
  u16*   S1b     = (u16*)  alloc((size_t)4096 * 512 * 2);
  float* S2f     = (float*)alloc((size_t)4096 * 512 * 4);
  u16*   S2b     = (u16*)  alloc((size_t)4096 * 512 * 2);
  u16*   X       = (u16*)  alloc((size_t)12288 * 512 * 2);
  float* Y1      = (float*)alloc((size_t)12288 * 256 * 4);
  u16*   Y1b     = (u16*)  alloc((size_t)12288 * 256 * 2);
  float* Y2      = (float*)alloc((size_t)12288 * 128 * 4);
  float* y1bias  = (float*)alloc(3 * 256 * 4);
  float* cvec    = (float*)alloc(512 * 4);
  float* psum    = (float*)alloc(256);
  u16*   poolb   = (u16*)  alloc((size_t)4096 * 512 * 2);

  prep_misc<<<16676, 256, 0, stream>>>(cf_w, cf_b, sib, proj_w, f1w, f1b, f2w,
                                       pde, out_w,
                                       wsum_b, projw_b, f1w512b, f2wb,
                                       cvec, psum, y1bias, outw_b);

  // h0 = emb[tok] @ proj_w^T + proj_b
  gemm64<true><<<dim3(64, 4), 256, 0, stream>>>(
      emb, tok, nullptr, projw_b, proj_b, 0, 1.f, h0f, h0b, 4096, 512, 512);
  // S1, S2
  gemm64<false><<<dim3(64, 4), 256, 0, stream>>>(
      nullptr, nullptr, h0b, wsum_b, cvec, 0, 1.f, S1f, S1b, 4096, 512, 512);
  gemm64<false><<<dim3(64, 4), 256, 0, stream>>>(
      nullptr, nullptr, S1b, wsum_b, cvec, 0, 2.f, S2f, S2b, 4096, 512, 512);

  // policy, 3 levels batched
  mean_ln_concat_b<<<3072, 256, 0, stream>>>(h0f, S1f, S2f, dep, in_g, in_b, X);
  gemm64<false><<<dim3(192, 2), 256, 0, stream>>>(
      nullptr, nullptr, X, f1w512b, y1bias, 256, 1.f, Y1, nullptr, 12288, 256, 512);
  ln_relu_b256<<<3072, 256, 0, stream>>>(Y1, n1g, n1b, Y1b);
  gemm64<false><<<dim3(192, 1), 256, 0, stream>>>(
      nullptr, nullptr, Y1b, f2wb, f2bias, 0, 1.f, Y2, nullptr, 12288, 128, 256);
  ln_policy128<<<3072, 256, 0, stream>>>(Y2, n2g, n2b, pow_w, pow_b, psum);

  // S3 GEMM fused with pooling (128^2, proven)
  gemm_pool<<<dim3(32, 4), 256, 0, stream>>>(
      S2b, wsum_b, cvec, 4.f, h0f, S1f, S2f, psum, poolb, 4096, 512, 512);

  // out = pooled @ out_w^T + out_b (4096 x 32000 x 512)
  // B-resident, 8 waves (2 waves/SIMD)
  gemmV<<<250, 512, 0, stream>>>(poolb, outw_b, out_b, out, 4096, 32000, 512);
}

// Round 19
// 381.456 us; speedup vs baseline: 1.2263x; 1.0198x over previous
//
#include <hip/hip_runtime.h>

typedef unsigned short u16;
using bf16x8 = __attribute__((ext_vector_type(8))) short;
using f32x4  = __attribute__((ext_vector_type(4))) float;

#define SIB_SCALE_F 0.04419417382415922f   // 1/sqrt(512)

__device__ __forceinline__ u16 f2b(float f) {
  unsigned u = __builtin_bit_cast(unsigned, f);
  return (u16)((u + 0x7FFFu + ((u >> 16) & 1u)) >> 16);   // RNE
}

__device__ __forceinline__ float wred(float v) {
  #pragma unroll
  for (int m = 1; m < 64; m <<= 1) v += __shfl_xor(v, m);
  return v;
}

__device__ __forceinline__ void gload16(const void* g, void* l) {
  __builtin_amdgcn_global_load_lds(
      (const __attribute__((address_space(1))) unsigned int*)g,
      (__attribute__((address_space(3))) unsigned int*)l, 16, 0, 0);
}

// ---------------------------------------------------------------------------
// PERSISTENT 256x256 bf16 MFMA GEMM, 8-phase pipeline (R13-proven best).
// Staggered m-tile order (R11, -14us) + NT float4 epilogue stores (R13).
// ---------------------------------------------------------------------------
__global__ __launch_bounds__(512, 2) void gemmP(
    const u16* __restrict__ A, const u16* __restrict__ B,
    const float* __restrict__ bias,
    float* __restrict__ C, int M, int N, int K, int MT)
{
  __shared__ u16 lds[65536];   // A: [0,32768) ; B: [32768,65536)  (u16 units)
  const int t = threadIdx.x, w = t >> 6, lane = t & 63;
  const int wm = w >> 2, wn = w & 3;
  const int r16 = lane & 15, ks = lane >> 4;

  const int bn = blockIdx.y * 256;
  const int mg = blockIdx.x;
  const int NT = K >> 6;
  const int stag = blockIdx.y & (MT - 1);     // burst de-synchronization

  auto stageH = [&](const u16* __restrict__ G, int grow0, int kt, int half, int opBase) {
    const int k0 = kt << 6;
    u16* dst = lds + opBase + ((kt & 1) << 14) + (half << 13);
    #pragma unroll
    for (int j = 0; j < 2; ++j) {
      const int r = half * 128 + j * 64 + w * 8 + (lane >> 3);
      const int s = (lane & 7) ^ (r & 7);
      gload16(G + (size_t)(grow0 + r) * K + k0 + s * 8,
              dst + j * 4096 + w * 512);
    }
  };

  for (int mt0 = 0; mt0 < MT; ++mt0) {
    const int mt = (mt0 + stag) & (MT - 1);
    const int bm = (mg * MT + mt) * 256;

    f32x4 acc[8][4];
    #pragma unroll
    for (int m = 0; m < 8; ++m)
      #pragma unroll
      for (int n = 0; n < 4; ++n) {
        f32x4 z = {0.f, 0.f, 0.f, 0.f};
        acc[m][n] = z;
      }

    __builtin_amdgcn_sched_barrier(0);
    stageH(A, bm, 0, 0, 0);
    stageH(A, bm, 0, 1, 0);
    stageH(B, bn, 0, 0, 32768);
    stageH(B, bn, 0, 1, 32768);
    __builtin_amdgcn_sched_barrier(0);
    stageH(B, bn, 1, 0, 32768);
    stageH(B, bn, 1, 1, 32768);
    asm volatile("s_waitcnt vmcnt(4)" ::: "memory");
    __builtin_amdgcn_sched_barrier(0);
    __builtin_amdgcn_s_barrier();

    for (int kt = 0; kt < NT; ++kt) {
      const u16* Ab = lds + ((kt & 1) << 14);
      const u16* Bb = lds + 32768 + ((kt & 1) << 14);
      bf16x8 bfr[4][2];

      #pragma unroll
      for (int p = 0; p < 4; ++p) {
        bf16x8 af2[2][2];
        #pragma unroll
        for (int i = 0; i < 2; ++i) {
          const int row = wm * 128 + (2 * p + i) * 16 + r16;
          af2[i][0] = *(const bf16x8*)(Ab + row * 64 + ((ks ^ (row & 7)) << 3));
          af2[i][1] = *(const bf16x8*)(Ab + row * 64 + (((4 + ks) ^ (row & 7)) << 3));
        }
        if (p == 0) {
          #pragma unroll
          for (int n = 0; n < 4; ++n) {
            const int row = wn * 64 + n * 16 + r16;
            bfr[n][0] = *(const bf16x8*)(Bb + row * 64 + ((ks ^ (row & 7)) << 3));
            bfr[n][1] = *(const bf16x8*)(Bb + row * 64 + (((4 + ks) ^ (row & 7)) << 3));
          }
        }
        if (p == 0 && kt + 1 < NT) stageH(A, bm, kt + 1, 0, 0);
        if (p == 1 && kt + 1 < NT) stageH(A, bm, kt + 1, 1, 0);
        if (p == 2 && kt + 2 < NT) stageH(B, bn, kt + 2, 0, 32768);
        if (p == 3) {
          if (kt + 2 < NT) {
            stageH(B, bn, kt + 2, 1, 32768);
            asm volatile("s_waitcnt vmcnt(4)" ::: "memory");
          } else {
            asm volatile("s_waitcnt vmcnt(0)" ::: "memory");
          }
          __builtin_amdgcn_sched_barrier(0);
        }
        __builtin_amdgcn_s_barrier();
        asm volatile("s_waitcnt lgkmcnt(0)" ::: "memory");
        __builtin_amdgcn_sched_barrier(0);
        __builtin_amdgcn_s_setprio(1);
        #pragma unroll
        for (int i = 0; i < 2; ++i)
          #pragma unroll
          for (int n = 0; n < 4; ++n) {
            acc[2 * p + i][n] = __builtin_amdgcn_mfma_f32_16x16x32_bf16(
                bfr[n][0], af2[i][0], acc[2 * p + i][n], 0, 0, 0);
            acc[2 * p + i][n] = __builtin_amdgcn_mfma_f32_16x16x32_bf16(
                bfr[n][1], af2[i][1], acc[2 * p + i][n], 0, 0, 0);
          }
        __builtin_amdgcn_s_setprio(0);
        __builtin_amdgcn_s_barrier();
      }
    }

    #pragma unroll
    for (int m = 0; m < 8; ++m) {
      const int grow = bm + wm * 128 + m * 16 + r16;
      float* Crow = C + (size_t)grow * N;
      #pragma unroll
      for (int n = 0; n < 4; ++n) {
        const int gcol = bn + wn * 64 + n * 16 + ks * 4;
        const float4 bv = *(const float4*)(bias + gcol);
        f32x4 o;
        o[0] = acc[m][n][0] + bv.x;
        o[1] = acc[m][n][1] + bv.y;
        o[2] = acc[m][n][2] + bv.z;
        o[3] = acc[m][n][3] + bv.w;
        __builtin_nontemporal_store(o, (f32x4*)(Crow + gcol));
      }
    }
  }
}

// ---------------------------------------------------------------------------
// Small GEMM, 64x128 tile, BK=32, 256 thr, swapped-operand float4 epilogue.
// GATHER: A rows = bf16(Afp[tok[row]]), K must be 512.
// ---------------------------------------------------------------------------
template <bool GATHER>
__global__ __launch_bounds__(256) void gemm64(
    const float* __restrict__ Afp, const int* __restrict__ tok,
    const u16* __restrict__ A, const u16* __restrict__ B,
    const float* __restrict__ bias, int blvl, float bscale,
    float* __restrict__ C, u16* __restrict__ Cb,
    int M, int N, int K)
{
  __shared__ u16 ldsA[64 * 32];    // 4 KB
  __shared__ u16 ldsB[128 * 32];   // 8 KB
  const int t = threadIdx.x, w = t >> 6, lane = t & 63;
  const int r16 = lane & 15, ks = lane >> 4;

  const int nb = gridDim.x * gridDim.y;
  const int lid = blockIdx.y * gridDim.x + blockIdx.x;
  const int chunk = nb >> 3;
  const int nlid = (lid & 7) * chunk + (lid >> 3);
  const int bm = (nlid % gridDim.x) * 64;
  const int bn = (nlid / gridDim.x) * 128;

  const int srow = t >> 2, sslot = t & 3;

  f32x4 acc[4][2];
  #pragma unroll
  for (int m = 0; m < 4; ++m)
    #pragma unroll
    for (int n = 0; n < 2; ++n) {
      f32x4 z = {0.f, 0.f, 0.f, 0.f};
      acc[m][n] = z;
    }

  for (int k0 = 0; k0 < K; k0 += 32) {
    if (k0) __syncthreads();
    {
      const int row = srow;                       // 0..63
      const int sl = sslot ^ ((row >> 1) & 3);
      if constexpr (GATHER) {
        const float* src = Afp + (size_t)tok[bm + row] * 512 + k0 + sl * 8;
        const float4 a0 = *(const float4*)src;
        const float4 a1 = *(const float4*)(src + 4);
        bf16x8 v;
        v[0] = (short)f2b(a0.x); v[1] = (short)f2b(a0.y);
        v[2] = (short)f2b(a0.z); v[3] = (short)f2b(a0.w);
        v[4] = (short)f2b(a1.x); v[5] = (short)f2b(a1.y);
        v[6] = (short)f2b(a1.z); v[7] = (short)f2b(a1.w);
        *(bf16x8*)(ldsA + t * 8) = v;
      } else {
        gload16(A + (size_t)(bm + row) * K + k0 + sl * 8, ldsA + w * 512);
      }
    }
    #pragma unroll
    for (int i = 0; i < 2; ++i) {
      const int row = i * 64 + srow;
      const int sl = sslot ^ ((row >> 1) & 3);
      gload16(B + (size_t)(bn + row) * K + k0 + sl * 8,
              ldsB + i * 2048 + w * 512);
    }
    __syncthreads();

    bf16x8 af[4], bfr[2];
    #pragma unroll
    for (int m = 0; m < 4; ++m) {
      const int row = m * 16 + r16;
      af[m] = *(const bf16x8*)(ldsA + row * 32 + ((ks ^ ((row >> 1) & 3)) << 3));
    }
    #pragma unroll
    for (int n = 0; n < 2; ++n) {
      const int row = w * 32 + n * 16 + r16;
      bfr[n] = *(const bf16x8*)(ldsB + row * 32 + ((ks ^ ((row >> 1) & 3)) << 3));
    }
    #pragma unroll
    for (int m = 0; m < 4; ++m)
      #pragma unroll
      for (int n = 0; n < 2; ++n)
        acc[m][n] = __builtin_amdgcn_mfma_f32_16x16x32_bf16(bfr[n], af[m], acc[m][n], 0, 0, 0);
  }

  const float* be = bias + (size_t)(bm >> 12) * blvl;
  #pragma unroll
  for (int m = 0; m < 4; ++m) {
    const int grow = bm + m * 16 + r16;
    #pragma unroll
    for (int n = 0; n < 2; ++n) {
      const int gcol = bn + w * 32 + n * 16 + ks * 4;
      const float4 bv = *(const float4*)(be + gcol);
      float4 o;
      o.x = acc[m][n][0] + bv.x * bscale;
      o.y = acc[m][n][1] + bv.y * bscale;
      o.z = acc[m][n][2] + bv.z * bscale;
      o.w = acc[m][n][3] + bv.w * bscale;
      const size_t idx = (size_t)grow * N + gcol;
      *(float4*)(C + idx) = o;
      if (Cb) {
        ushort4 ob = { f2b(o.x), f2b(o.y), f2b(o.z), f2b(o.w) };
        *(ushort4*)(Cb + idx) = ob;
      }
    }
  }
}

// ---------------------------------------------------------------------------
// bf16 MFMA GEMM, 128x128 tile, BK=32, swapped-operand epilogue (S3+POOL).
// ---------------------------------------------------------------------------
__global__ __launch_bounds__(256) void gemm_pool(
    const u16* __restrict__ A, const u16* __restrict__ B,
    const float* __restrict__ bias, float bscale,
    const float* __restrict__ h0f, const float* __restrict__ S1f,
    const float* __restrict__ S2f, const float* __restrict__ psum,
    u16* __restrict__ P,
    int M, int N, int K)
{
  __shared__ u16 ldsA[128 * 32];
  __shared__ u16 ldsB[128 * 32];
  const int t = threadIdx.x;
  const int w = t >> 6;
  const int lane = t & 63;
  const int wr = w >> 1, wc = w & 1;

  const int nb = gridDim.x * gridDim.y;
  const int lid = blockIdx.y * gridDim.x + blockIdx.x;
  const int chunk = nb >> 3;
  const int nlid = (lid & 7) * chunk + (lid >> 3);
  const int bx = nlid % gridDim.x, by = nlid / gridDim.x;

  const int bm = bx * 128, bn = by * 128;
  const int r16 = lane & 15, ks = lane >> 4;
  const int srow = t >> 2, sslot = t & 3;

  f32x4 acc[4][4];
  #pragma unroll
  for (int m = 0; m < 4; ++m)
    #pragma unroll
    for (int n = 0; n < 4; ++n) {
      f32x4 z = {0.f, 0.f, 0.f, 0.f};
      acc[m][n] = z;
    }

  for (int k0 = 0; k0 < K; k0 += 32) {
    if (k0) __syncthreads();
    #pragma unroll
    for (int i = 0; i < 2; ++i) {
      const int row = srow + i * 64;
      const int sl = sslot ^ ((row >> 1) & 3);
      gload16(A + (size_t)(bm + row) * K + k0 + sl * 8,
              ldsA + (i * 2048 + w * 512));
      gload16(B + (size_t)(bn + row) * K + k0 + sl * 8,
              ldsB + (i * 2048 + w * 512));
    }
    __syncthreads();

    bf16x8 af[4], bfr[4];
    #pragma unroll
    for (int m = 0; m < 4; ++m) {
      const int row = wr * 64 + m * 16 + r16;
      af[m] = *(const bf16x8*)(ldsA + row * 32 + ((ks ^ ((row >> 1) & 3)) << 3));
    }
    #pragma unroll
    for (int n = 0; n < 4; ++n) {
      const int row = wc * 64 + n * 16 + r16;
      bfr[n] = *(const bf16x8*)(ldsB + row * 32 + ((ks ^ ((row >> 1) & 3)) << 3));
    }
    #pragma unroll
    for (int m = 0; m < 4; ++m)
      #pragma unroll
      for (int n = 0; n < 4; ++n)
        acc[m][n] = __builtin_amdgcn_mfma_f32_16x16x32_bf16(bfr[n], af[m], acc[m][n], 0, 0, 0);
  }

  const float a0 = (psum[0] * (1.f / 4096.f) >= 0.5f) ? 1.f : 0.f;
  const float a1 = a0 * ((psum[1] * (1.f / 4096.f) >= 0.5f) ? 1.f : 0.f);
  const float a2 = a1 * ((psum[2] * (1.f / 4096.f) >= 0.5f) ? 1.f : 0.f);
  const float cnt = 1.f + a0 * 2.f + a1 * 4.f + a2 * 8.f;
  const float inv = 1.f / fmaxf(cnt, 1e-8f);

  #pragma unroll
  for (int m = 0; m < 4; ++m) {
    const int grow = bm + wr * 64 + m * 16 + r16;
    #pragma unroll
    for (int n = 0; n < 4; ++n) {
      const int gcol = bn + wc * 64 + n * 16 + ks * 4;
      const float4 bv = *(const float4*)(bias + gcol);
      float4 o;
      o.x = acc[m][n][0] + bv.x * bscale;
      o.y = acc[m][n][1] + bv.y * bscale;
      o.z = acc[m][n][2] + bv.z * bscale;
      o.w = acc[m][n][3] + bv.w * bscale;
      const size_t idx = (size_t)grow * N + gcol;
      const float4 h = *(const float4*)(h0f + idx);
      const float4 s1 = *(const float4*)(S1f + idx);
      const float4 s2 = *(const float4*)(S2f + idx);
      ushort4 ob;
      ob.x = f2b((h.x + a0 * s1.x + a1 * s2.x + a2 * o.x) * inv);
      ob.y = f2b((h.y + a0 * s1.y + a1 * s2.y + a2 * o.y) * inv);
      ob.z = f2b((h.z + a0 * s1.z + a1 * s2.z + a2 * o.z) * inv);
      ob.w = f2b((h.w + a0 * s1.w + a1 * s2.w + a2 * o.w) * inv);
      *(ushort4*)(P + idx) = ob;
    }
  }
}

// ---------------------------------------------------------------------------
// fused weight prep + out_w conversion, role-dispatched (grid 16676)
// ---------------------------------------------------------------------------
__global__ __launch_bounds__(256) void prep_misc(
    const float* __restrict__ cf_w, const float* __restrict__ cf_b,
    const float* __restrict__ sib, const float* __restrict__ proj_w,
    const float* __restrict__ f1w, const float* __restrict__ f1b,
    const float* __restrict__ f2w, const float* __restrict__ pde,
    const float* __restrict__ out_w,
    u16* __restrict__ wsum_b, u16* __restrict__ projw_b,
    u16* __restrict__ f1w512b, u16* __restrict__ f2wb,
    float* __restrict__ cvec, float* __restrict__ psum,
    float* __restrict__ y1bias, u16* __restrict__ outw_b)
{
  const int b = blockIdx.x, t = threadIdx.x;
  if (b >= 676) {
    const int idx = (b - 676) * 256 + t;
    const float4 v = ((const float4*)out_w)[idx];
    ushort4 o = { f2b(v.x), f2b(v.y), f2b(v.z), f2b(v.w) };
    ((ushort4*)outw_b)[idx] = o;
  } else if (b < 256) {
    const int idx = b * 256 + t;
    const float4 a = ((const float4*)cf_w)[idx];
    const float4 c = ((const float4*)(cf_w + 262144))[idx];
    ushort4 o = { f2b(a.x + c.x), f2b(a.y + c.y), f2b(a.z + c.z), f2b(a.w + c.w) };
    ((ushort4*)wsum_b)[idx] = o;
  } else if (b < 512) {
    const int idx = (b - 256) * 256 + t;
    const float4 v = ((const float4*)proj_w)[idx];
    ushort4 o = { f2b(v.x), f2b(v.y), f2b(v.z), f2b(v.w) };
    ((ushort4*)projw_b)[idx] = o;
  } else if (b < 640) {
    const int fi = (b - 512) * 256 + t;
    const int row = fi >> 7, c4 = fi & 127;
    const float4 v = *(const float4*)(f1w + (size_t)row * 640 + c4 * 4);
    ushort4 o = { f2b(v.x), f2b(v.y), f2b(v.z), f2b(v.w) };
    ((ushort4*)f1w512b)[row * 128 + c4] = o;
  } else if (b < 672) {
    const int idx = (b - 640) * 256 + t;
    const float4 v = ((const float4*)f2w)[idx];
    ushort4 o = { f2b(v.x), f2b(v.y), f2b(v.z), f2b(v.w) };
    ((ushort4*)f2wb)[idx] = o;
  } else if (b < 675) {
    const int l = b - 672, j = t;
    const float* wrow = f1w + (size_t)j * 640 + 512;
    const float* p = pde + l * 128;
    float s = f1b[j];
    #pragma unroll 4
    for (int k = 0; k < 128; ++k) s += wrow[k] * p[k];
    y1bias[l * 256 + j] = s;
  } else {
    cvec[t]       = cf_b[t]       + cf_b[512 + t] + SIB_SCALE_F * (sib[t]       + sib[512 + t]);
    cvec[256 + t] = cf_b[256 + t] + cf_b[768 + t] + SIB_SCALE_F * (sib[256 + t] + sib[768 + t]);
    if (t < 3) psum[t] = 0.f;
  }
}

// ---------------------------------------------------------------------------
// batched policy input over 3 levels: X[g] = bf16(LN(S_l/2^l + 0.01*dep_l))
// ---------------------------------------------------------------------------
__global__ __launch_bounds__(256) void mean_ln_concat_b(
    const float* __restrict__ S0, const float* __restrict__ S1,
    const float* __restrict__ S2,
    const float* __restrict__ dep,
    const float* __restrict__ g, const float* __restrict__ b,
    u16* __restrict__ X)
{
  const int wid = threadIdx.x >> 6, lane = threadIdx.x & 63;
  const int gr = blockIdx.x * 4 + wid;          // 0..12287
  const int l = gr >> 12, n = gr & 4095;
  const float* Sr = (l == 0 ? S0 : l == 1 ? S1 : S2) + (size_t)n * 512;
  const float invM = (l == 0 ? 1.f : l == 1 ? 0.5f : 0.25f);
  const float* depl = dep + 512 * l;
  const int c0 = lane * 8;
  float x[8];
  float s = 0.f, sq = 0.f;
  #pragma unroll
  for (int i = 0; i < 8; ++i) {
    const float v = Sr[c0 + i] * invM + 0.01f * depl[c0 + i];
    x[i] = v; s += v; sq += v * v;
  }
  s = wred(s); sq = wred(sq);
  const float mean = s * (1.f / 512.f);
  const float var = sq * (1.f / 512.f) - mean * mean;
  const float rs = rsqrtf(var + 1e-5f);
  ushort4 o0, o1;
  o0.x = f2b((x[0] - mean) * rs * g[c0 + 0] + b[c0 + 0]);
  o0.y = f2b((x[1] - mean) * rs * g[c0 + 1] + b[c0 + 1]);
  o0.z = f2b((x[2] - mean) * rs * g[c0 + 2] + b[c0 + 2]);
  o0.w = f2b((x[3] - mean) * rs * g[c0 + 3] + b[c0 + 3]);
  o1.x = f2b((x[4] - mean) * rs * g[c0 + 4] + b[c0 + 4]);
  o1.y = f2b((x[5] - mean) * rs * g[c0 + 5] + b[c0 + 5]);
  o1.z = f2b((x[6] - mean) * rs * g[c0 + 6] + b[c0 + 6]);
  o1.w = f2b((x[7] - mean) * rs * g[c0 + 7] + b[c0 + 7]);
  ushort4* Xr = (ushort4*)(X + (size_t)gr * 512);
  Xr[lane * 2]     = o0;
  Xr[lane * 2 + 1] = o1;
}

// LN + relu over 256 cols, fp32 in -> bf16 out
__global__ __launch_bounds__(256) void ln_relu_b256(
    const float* __restrict__ X, const float* __restrict__ g,
    const float* __restrict__ b, u16* __restrict__ O)
{
  const int wid = threadIdx.x >> 6, lane = threadIdx.x & 63;
  const int n = blockIdx.x * 4 + wid;
  const float* Xr = X + (size_t)n * 256;
  float x[4];
  float s = 0.f, sq = 0.f;
  #pragma unroll
  for (int i = 0; i < 4; ++i) {
    x[i] = Xr[lane * 4 + i]; s += x[i]; sq += x[i] * x[i];
  }
  s = wred(s); sq = wred(sq);
  const float mean = s * (1.f / 256.f);
  const float var = sq * (1.f / 256.f) - mean * mean;
  const float rs = rsqrtf(var + 1e-5f);
  ushort4 o;
  o.x = f2b(fmaxf((x[0] - mean) * rs * g[lane * 4 + 0] + b[lane * 4 + 0], 0.f));
  o.y = f2b(fmaxf((x[1] - mean) * rs * g[lane * 4 + 1] + b[lane * 4 + 1], 0.f));
  o.z = f2b(fmaxf((x[2] - mean) * rs * g[lane * 4 + 2] + b[lane * 4 + 2], 0.f));
  o.w = f2b(fmaxf((x[3] - mean) * rs * g[lane * 4 + 3] + b[lane * 4 + 3], 0.f));
  ((ushort4*)(O + (size_t)n * 256))[lane] = o;
}

// fused: LN(128) + relu + dot(pow_w) + sigmoid + clip + per-level atomicAdd
__global__ __launch_bounds__(256) void ln_policy128(
    const float* __restrict__ Y2, const float* __restrict__ g,
    const float* __restrict__ b, const float* __restrict__ pw,
    const float* __restrict__ pb, float* __restrict__ psum)
{
  __shared__ float part[4];
  const int wid = threadIdx.x >> 6, lane = threadIdx.x & 63;
  const int gr = blockIdx.x * 4 + wid;
  const float* Xr = Y2 + (size_t)gr * 128;
  float x[2];
  float s = 0.f, sq = 0.f;
  #pragma unroll
  for (int i = 0; i < 2; ++i) {
    x[i] = Xr[lane * 2 + i]; s += x[i]; sq += x[i] * x[i];
  }
  s = wred(s); sq = wred(sq);
  const float mean = s * (1.f / 128.f);
  const float var = sq * (1.f / 128.f) - mean * mean;
  const float rs = rsqrtf(var + 1e-5f);
  float z = 0.f;
  #pragma unroll
  for (int i = 0; i < 2; ++i) {
    const int c = lane * 2 + i;
    const float v = fmaxf((x[i] - mean) * rs * g[c] + b[c], 0.f);
    z += v * pw[c];
  }
  z = wred(z);
  if (lane == 0) {
    const float p = 1.f / (1.f + expf(-(z + pb[0])));
    part[wid] = fminf(fmaxf(p, 1e-7f), 1.f - 1e-7f);
  }
  __syncthreads();
  if (threadIdx.x == 0)
    atomicAdd(psum + (gr >> 12), part[0] + part[1] + part[2] + part[3]);
}

// ---------------------------------------------------------------------------
extern "C" void kernel_launch(void* const* d_in, const int* in_sizes, int n_in,
                              void* d_out, int out_size, void* d_ws, size_t ws_size,
                              hipStream_t stream) {
  const int*   tok    = (const int*)  d_in[0];
  const float* emb    = (const float*)d_in[1];
  const float* proj_w = (const float*)d_in[2];
  const float* proj_b = (const float*)d_in[3];
  const float* cf_w   = (const float*)d_in[4];
  const float* cf_b   = (const float*)d_in[5];
  const float* in_g   = (const float*)d_in[6];
  const float* in_b   = (const float*)d_in[7];
  const float* pde    = (const float*)d_in[8];
  const float* f1w    = (const float*)d_in[9];
  const float* f1b    = (const float*)d_in[10];
  const float* n1g    = (const float*)d_in[11];
  const float* n1b    = (const float*)d_in[12];
  const float* f2w    = (const float*)d_in[13];
  const float* f2bias = (const float*)d_in[14];
  const float* n2g    = (const float*)d_in[15];
  const float* n2b    = (const float*)d_in[16];
  const float* pow_w  = (const float*)d_in[17];
  const float* pow_b  = (const float*)d_in[18];
  const float* sib    = (const float*)d_in[19];
  const float* dep    = (const float*)d_in[20];
  const float* out_w  = (const float*)d_in[21];
  const float* out_b  = (const float*)d_in[22];
  float* out = (float*)d_out;

  char* ws = (char*)d_ws;
  size_t off = 0;
  auto alloc = [&](size_t bytes) -> void* {
    void* p = ws + off;
    off += (bytes + 255) & ~(size_t)255;
    return p;
  };
  u16*   outw_b  = (u16*)  alloc((size_t)32000 * 512 * 2);
  u16*   projw_b = (u16*)  alloc((size_t)512 * 512 * 2);
  u16*   wsum_b  = (u16*)  alloc((size_t)512 * 512 * 2);
  u16*   f1w512b = (u16*)  alloc((size_t)256 * 512 * 2);
  u16*   f2wb    = (u16*)  alloc((size_t)128 * 256 * 2);
  float* h0f     = (float*)alloc((size_t)4096 * 512 * 4);
  u16*   h0b     = (u16*)  alloc((size_t)4096 * 512 * 2);
  float* S1f     = (float*)alloc((size_t)4096 * 512 * 4);
  u16*   S1b     = (u16*)  alloc((size_t)4096 * 512 * 2);
  float* S2f     = (float*)alloc((size_t)4096 * 512 * 4);
  u16*   S2b     = (u16*)  alloc((size_t)4096 * 512 * 2);
  u16*   X       = (u16*)  alloc((size_t)12288 * 512 * 2);
  float* Y1      = (float*)alloc((size_t)12288 * 256 * 4);
  u16*   Y1b     = (u16*)  alloc((size_t)12288 * 256 * 2);
  float* Y2      = (float*)alloc((size_t)12288 * 128 * 4);
  float* y1bias  = (float*)alloc(3 * 256 * 4);
  float* cvec    = (float*)alloc(512 * 4);
  float* psum    = (float*)alloc(256);
  u16*   poolb   = (u16*)  alloc((size_t)4096 * 512 * 2);

  prep_misc<<<16676, 256, 0, stream>>>(cf_w, cf_b, sib, proj_w, f1w, f1b, f2w,
                                       pde, out_w,
                                       wsum_b, projw_b, f1w512b, f2wb,
                                       cvec, psum, y1bias, outw_b);

  // h0 = emb[tok] @ proj_w^T + proj_b
  gemm64<true><<<dim3(64, 4), 256, 0, stream>>>(
      emb, tok, nullptr, projw_b, proj_b, 0, 1.f, h0f, h0b, 4096, 512, 512);
  // S1, S2
  gemm64<false><<<dim3(64, 4), 256, 0, stream>>>(
      nullptr, nullptr, h0b, wsum_b, cvec, 0, 1.f, S1f, S1b, 4096, 512, 512);
  gemm64<false><<<dim3(64, 4), 256, 0, stream>>>(
      nullptr, nullptr, S1b, wsum_b, cvec, 0, 2.f, S2f, S2b, 4096, 512, 512);

  // policy, 3 levels batched
  mean_ln_concat_b<<<3072, 256, 0, stream>>>(h0f, S1f, S2f, dep, in_g, in_b, X);
  gemm64<false><<<dim3(192, 2), 256, 0, stream>>>(
      nullptr, nullptr, X, f1w512b, y1bias, 256, 1.f, Y1, nullptr, 12288, 256, 512);
  ln_relu_b256<<<3072, 256, 0, stream>>>(Y1, n1g, n1b, Y1b);
  gemm64<false><<<dim3(192, 1), 256, 0, stream>>>(
      nullptr, nullptr, Y1b, f2wb, f2bias, 0, 1.f, Y2, nullptr, 12288, 128, 256);
  ln_policy128<<<3072, 256, 0, stream>>>(Y2, n2g, n2b, pow_w, pow_b, psum);

  // S3 GEMM fused with pooling (128^2, proven)
  gemm_pool<<<dim3(32, 4), 256, 0, stream>>>(
      S2b, wsum_b, cvec, 4.f, h0f, S1f, S2f, psum, poolb, 4096, 512, 512);

  // out = pooled @ out_w^T + out_b (4096 x 32000 x 512)
  // persistent 256x256 8-phase, staggered m-tiles, NT stores (R13 best)
  gemmP<<<dim3(2, 125), 512, 0, stream>>>(poolb, outw_b, out_b,
                                          out, 4096, 32000, 512, 8);
}